// Round 1
// baseline (1425.934 us; speedup 1.0000x reference)
//
#include <hip/hip_runtime.h>
#include <stdint.h>

#define CNT 8192
#define DIM 128

// ---- workspace layout (bytes) ----
#define OFF_XN      ((size_t)0)                            // 6*CNT*DIM*4 = 25,165,824
#define OFF_POS     ((size_t)6*CNT*DIM*4)                  // 3*CNT floats
#define OFF_NEG     (OFF_POS + (size_t)3*CNT*4)            // 3*CNT floats
#define OFF_ROWPART (OFF_NEG + (size_t)3*CNT*4)            // 3*64*CNT u64
#define OFF_COLPART (OFF_ROWPART + (size_t)3*64*CNT*8)     // 3*64*CNT u64
#define OFF_FIN     (OFF_COLPART + (size_t)3*64*CNT*8)     // 2*3*CNT u64
#define OFF_BCE     (OFF_FIN + (size_t)2*3*CNT*8)          // 200 floats
// total ~48.6 MiB

__device__ __forceinline__ unsigned int ordf(float f){
  unsigned int u = __float_as_uint(f);
  return (u & 0x80000000u) ? ~u : (u | 0x80000000u);
}
__device__ __forceinline__ float unordf(unsigned int o){
  unsigned int b = (o & 0x80000000u) ? (o & 0x7FFFFFFFu) : ~o;
  return __uint_as_float(b);
}

// row-normalize: one wave per row (128 f32 = 2/lane)
__global__ __launch_bounds__(256) void knorm(const float* __restrict__ in, float* __restrict__ xn){
  const int row  = blockIdx.x*4 + (threadIdx.x>>6);
  const int lane = threadIdx.x & 63;
  const float2 v = *(const float2*)(in + (size_t)row*DIM + lane*2);
  float ss = v.x*v.x + v.y*v.y;
  #pragma unroll
  for (int m=1;m<64;m<<=1) ss += __shfl_xor(ss, m, 64);
  const float n = sqrtf(ss);
  float2 o; o.x = v.x/n; o.y = v.y/n;
  *(float2*)(xn + (size_t)row*DIM + lane*2) = o;
}

__device__ __forceinline__ float wave_dot(const float* __restrict__ a, const float* __restrict__ b, int lane){
  const float2 va = *(const float2*)(a + lane*2);
  const float2 vb = *(const float2*)(b + lane*2);
  float s = va.x*vb.x + va.y*vb.y;
  #pragma unroll
  for (int m=1;m<64;m<<=1) s += __shfl_xor(s, m, 64);
  return s;
}

// positive pair dots: pos[p][i] = dot(X_p[i], Y_p[i])
__global__ __launch_bounds__(256) void kdiag(const float* __restrict__ xn, float* __restrict__ pos){
  const int t = blockIdx.x*4 + (threadIdx.x>>6);
  const int lane = threadIdx.x & 63;
  const int p = t >> 13, i = t & (CNT-1);
  const int xo[3] = {0, 2*CNT, 4*CNT};
  const int yo[3] = {CNT, 5*CNT, 3*CNT};
  float d = wave_dot(xn + (size_t)(xo[p]+i)*DIM, xn + (size_t)(yo[p]+i)*DIM, lane);
  if (lane == 0) pos[p*CNT + i] = d;
}

// fused GEMM + dm + row/col min-argmin partials.
// grid (64, 64, 3), 256 threads, 128x128 tile, K=128 in one shot.
// LDS k-major with XOR swizzle (row ^ (k&28)) -> conflict-free ds_read_b128.
__global__ __launch_bounds__(256) void kgemm(const float* __restrict__ xn,
    unsigned long long* __restrict__ rowpart, unsigned long long* __restrict__ colpart){
  __shared__ __align__(16) float Xs[DIM*128];
  __shared__ __align__(16) float Ys[DIM*128];
  const int pair = blockIdx.z;
  const int xo[3] = {0, 2*CNT, 4*CNT};
  const int yo[3] = {CNT, 5*CNT, 3*CNT};
  const float* __restrict__ X = xn + (size_t)xo[pair]*DIM;
  const float* __restrict__ Y = xn + (size_t)yo[pair]*DIM;
  const int brow = blockIdx.y*128, bcol = blockIdx.x*128;
  const int tid = threadIdx.x;

  #pragma unroll
  for (int it=0; it<16; ++it){
    const int f   = it*256 + tid;     // 0..4095
    const int row = f >> 5;           // 0..127
    const int kg  = f & 31;           // float4 group along K
    const float4 vx = *(const float4*)(X + (size_t)(brow+row)*DIM + kg*4);
    const float4 vy = *(const float4*)(Y + (size_t)(bcol+row)*DIM + kg*4);
    const int sr = row ^ ((kg & 7) << 2);   // == row ^ (k&28), same for the 4 k's
    Xs[(4*kg+0)*128 + sr] = vx.x;
    Xs[(4*kg+1)*128 + sr] = vx.y;
    Xs[(4*kg+2)*128 + sr] = vx.z;
    Xs[(4*kg+3)*128 + sr] = vx.w;
    Ys[(4*kg+0)*128 + sr] = vy.x;
    Ys[(4*kg+1)*128 + sr] = vy.y;
    Ys[(4*kg+2)*128 + sr] = vy.z;
    Ys[(4*kg+3)*128 + sr] = vy.w;
  }
  __syncthreads();

  const int r0 = (tid >> 4) * 8;
  const int c0 = (tid & 15) * 8;
  float acc[8][8];
  #pragma unroll
  for (int i=0;i<8;i++)
    #pragma unroll
    for (int j=0;j<8;j++) acc[i][j] = 0.0f;

  #pragma unroll 4
  for (int k=0;k<DIM;k++){
    const int s = k & 28;
    const float4 xa = *(const float4*)&Xs[k*128 + (r0 ^ s)];
    const float4 xb = *(const float4*)&Xs[k*128 + ((r0+4) ^ s)];
    const float4 ya = *(const float4*)&Ys[k*128 + (c0 ^ s)];
    const float4 yb = *(const float4*)&Ys[k*128 + ((c0+4) ^ s)];
    const float xr[8] = {xa.x,xa.y,xa.z,xa.w,xb.x,xb.y,xb.z,xb.w};
    const float yr[8] = {ya.x,ya.y,ya.z,ya.w,yb.x,yb.y,yb.z,yb.w};
    #pragma unroll
    for (int i=0;i<8;i++)
      #pragma unroll
      for (int j=0;j<8;j++)
        acc[i][j] = fmaf(xr[i], yr[j], acc[i][j]);
  }

  // dm = 1/dot + EPS_SIM (+BIG on diag)
  #pragma unroll
  for (int i=0;i<8;i++){
    #pragma unroll
    for (int j=0;j<8;j++){
      float dm = 1.0f/acc[i][j] + 0.01f;
      if (brow + r0 + i == bcol + c0 + j) dm += 99999.0f;
      acc[i][j] = dm;
    }
  }

  // per-row min over this block's 128 cols (reduce across the 16 tx lanes)
  #pragma unroll
  for (int i=0;i<8;i++){
    unsigned long long best = 0xFFFFFFFFFFFFFFFFull;
    #pragma unroll
    for (int j=0;j<8;j++){
      unsigned long long pk = ((unsigned long long)ordf(acc[i][j]) << 32) | (unsigned int)(bcol + c0 + j);
      best = pk < best ? pk : best;
    }
    #pragma unroll
    for (int m=1;m<16;m<<=1){
      unsigned long long o = __shfl_xor(best, m, 64);
      best = o < best ? o : best;
    }
    if ((tid & 15) == 0)
      rowpart[((size_t)pair*64 + blockIdx.x)*CNT + (brow + r0 + i)] = best;
  }

  __syncthreads();                 // done with Xs/Ys -> reuse Xs
  unsigned long long* colred = (unsigned long long*)Xs;

  // per-col min over this block's 128 rows (reduce 4 ty lanes in wave, then 4 waves via LDS)
  #pragma unroll
  for (int j=0;j<8;j++){
    unsigned long long best = 0xFFFFFFFFFFFFFFFFull;
    #pragma unroll
    for (int i=0;i<8;i++){
      unsigned long long pk = ((unsigned long long)ordf(acc[i][j]) << 32) | (unsigned int)(brow + r0 + i);
      best = pk < best ? pk : best;
    }
    #pragma unroll
    for (int m=16;m<64;m<<=1){
      unsigned long long o = __shfl_xor(best, m, 64);
      best = o < best ? o : best;
    }
    if ((tid & 63) < 16)
      colred[(tid>>6)*128 + (tid & 15)*8 + j] = best;
  }
  __syncthreads();
  if (tid < 128){
    unsigned long long b = colred[tid];
    #pragma unroll
    for (int w=1;w<4;w++){
      unsigned long long o = colred[w*128 + tid];
      b = o < b ? o : b;
    }
    colpart[((size_t)pair*64 + blockIdx.y)*CNT + (bcol + tid)] = b;
  }
}

// reduce 64 block-partials -> final row/col min per (pair, index)
__global__ __launch_bounds__(256) void kreduce(const unsigned long long* __restrict__ rowpart,
    const unsigned long long* __restrict__ colpart, unsigned long long* __restrict__ fin){
  const int e = blockIdx.x*4 + (threadIdx.x>>6);   // 0..49151
  const int lane = threadIdx.x & 63;
  const int kind = e / (3*CNT);
  const int rem  = e - kind*(3*CNT);
  const int p = rem >> 13, i = rem & (CNT-1);
  const unsigned long long* src = kind ? colpart : rowpart;
  unsigned long long v = src[((size_t)p*64 + lane)*CNT + i];
  #pragma unroll
  for (int m=1;m<64;m<<=1){
    unsigned long long o = __shfl_xor(v, m, 64);
    v = o < v ? o : v;
  }
  if (lane == 0) fin[(size_t)kind*(3*CNT) + rem] = v;
}

// select hard negative and compute its dot
__global__ __launch_bounds__(256) void kneg(const float* __restrict__ xn,
    const unsigned long long* __restrict__ fin, float* __restrict__ neg){
  const int e = blockIdx.x*4 + (threadIdx.x>>6);   // 0..24575
  const int lane = threadIdx.x & 63;
  const int p = e >> 13, i = e & (CNT-1);
  const int xo[3] = {0, 2*CNT, 4*CNT};
  const int yo[3] = {CNT, 5*CNT, 3*CNT};
  const unsigned long long rv = fin[p*CNT + i];
  const unsigned long long cv = fin[3*CNT + p*CNT + i];
  const float fr = unordf((unsigned int)(rv >> 32));
  const float fc = unordf((unsigned int)(cv >> 32));
  int orow;
  if (fr < fc) orow = yo[p] + (int)(rv & 0xFFFFFFFFull);   // idx_n = row_arg + cnt -> Y row
  else         orow = xo[p] + (int)(cv & 0xFFFFFFFFull);   // idx_n = col_arg       -> X row
  float d = wave_dot(xn + (size_t)(xo[p]+i)*DIM, xn + (size_t)orow*DIM, lane);
  if (lane == 0) neg[p*CNT + i] = d;
}

// per-alpha BCE (200 blocks). three passes: mean, std(ddof=1), bce.
__global__ __launch_bounds__(256) void kbce(const float* __restrict__ pos, const float* __restrict__ neg,
    float* __restrict__ bce){
  const int kk = blockIdx.x;
  const float a = -1.0f + 0.01f*(float)kk;
  const int tid = threadIdx.x;
  __shared__ float red[4];

  float s = 0.0f;
  for (int idx = tid; idx < 6*CNT; idx += 256){
    const float d = (idx < 3*CNT) ? pos[idx] : neg[idx - 3*CNT];
    const float om = 1.0f - d;
    const float dist = a*om + (1.0f - a)*sqrtf(2.0f*om + 1e-12f);
    s += dist;
  }
  #pragma unroll
  for (int m=1;m<64;m<<=1) s += __shfl_xor(s, m, 64);
  if ((tid & 63) == 0) red[tid>>6] = s;
  __syncthreads();
  const float mean = (red[0]+red[1]+red[2]+red[3]) / 49152.0f;
  __syncthreads();

  float ss = 0.0f;
  for (int idx = tid; idx < 6*CNT; idx += 256){
    const float d = (idx < 3*CNT) ? pos[idx] : neg[idx - 3*CNT];
    const float om = 1.0f - d;
    const float dist = a*om + (1.0f - a)*sqrtf(2.0f*om + 1e-12f);
    const float dd = dist - mean;
    ss += dd*dd;
  }
  #pragma unroll
  for (int m=1;m<64;m<<=1) ss += __shfl_xor(ss, m, 64);
  if ((tid & 63) == 0) red[tid>>6] = ss;
  __syncthreads();
  const float stdv = sqrtf((red[0]+red[1]+red[2]+red[3]) / 49151.0f);
  __syncthreads();

  float bs = 0.0f;
  for (int idx = tid; idx < 6*CNT; idx += 256){
    const float d = (idx < 3*CNT) ? pos[idx] : neg[idx - 3*CNT];
    const float om = 1.0f - d;
    const float dist = a*om + (1.0f - a)*sqrtf(2.0f*om + 1e-12f);
    const float pr = 1.0f/(1.0f + expf((dist - mean)/stdv));   // sigmoid(-(d-mean)/std)
    bs += (idx < 3*CNT) ? -logf(pr) : -logf(1.0f - pr);
  }
  #pragma unroll
  for (int m=1;m<64;m<<=1) bs += __shfl_xor(bs, m, 64);
  if ((tid & 63) == 0) red[tid>>6] = bs;
  __syncthreads();
  if (tid == 0) bce[kk] = (red[0]+red[1]+red[2]+red[3]) / 49152.0f;
}

// argmin(bce) -> alpha; losses, mask ratio, l_mean; write 8 outputs
__global__ __launch_bounds__(256) void kfinal(const float* __restrict__ pos, const float* __restrict__ neg,
    const float* __restrict__ bce, const float* __restrict__ l_a_adv, const float* __restrict__ l_p_adv,
    float* __restrict__ out){
  __shared__ float sal[2];
  __shared__ float red[4];
  const int tid = threadIdx.x;
  if (tid == 0){
    float best = bce[0]; int bk = 0;
    for (int k=1;k<200;k++){
      const float v = bce[k];
      if (v < best){ best = v; bk = k; }
    }
    const float aopt = -1.0f + 0.01f*(float)bk;
    sal[0] = aopt;              // alpha_opt
    sal[1] = aopt * 0.005f;     // alpha = 0*0.995 + aopt*(1-0.995)
  }
  __syncthreads();
  const float alpha = sal[1];

  float sc=0.f, sar=0.f, saa=0.f, sm=0.f, sla=0.f, slp=0.f;
  for (int i = tid; i < CNT; i += 256){
    const float pap = pos[i],        nap = neg[i];
    const float par = pos[CNT+i],    nar = neg[CNT+i];
    const float paa = pos[2*CNT+i],  naa = neg[2*CNT+i];
    const float cp = fminf(fmaxf(pap, -1.0f), 1.0f);
    const float cn = fminf(fmaxf(nap, -1.0f), 1.0f);
    const float m = (0.36f + acosf(cp) - acosf(cn) > 0.0f) ? 1.0f : 0.0f;
    #define DDIST(d) (alpha*(1.0f-(d)) + (1.0f-alpha)*sqrtf(2.0f*(1.0f-(d)) + 1e-12f))
    sc  += (DDIST(pap) - DDIST(nap)) * m;
    sar += (l_p_adv[i]*DDIST(par) - DDIST(nar)) * m;
    saa += (l_a_adv[i]*DDIST(paa) - DDIST(naa)) * m;
    sm  += m;
    sla += l_a_adv[i];
    slp += l_p_adv[i];
  }
  float vals[6] = {sc, sar, saa, sm, sla, slp};
  float tot[6];
  for (int v=0; v<6; v++){
    float x = vals[v];
    #pragma unroll
    for (int m2=1;m2<64;m2<<=1) x += __shfl_xor(x, m2, 64);
    __syncthreads();
    if ((tid & 63) == 0) red[tid>>6] = x;
    __syncthreads();
    tot[v] = red[0]+red[1]+red[2]+red[3];
  }
  if (tid == 0){
    const float lc  = tot[0] / (float)CNT;
    const float lar = tot[1] / (float)CNT;
    const float laa = tot[2] / (float)CNT;
    out[0] = (lc + lar + laa) / 3.0f;
    out[1] = lc;
    out[2] = lar;
    out[3] = laa;
    out[4] = (tot[4]/(float)CNT + tot[5]/(float)CNT) * 0.5f;
    out[5] = sal[1];
    out[6] = sal[0];
    out[7] = tot[3] / (float)CNT;
  }
}

extern "C" void kernel_launch(void* const* d_in, const int* in_sizes, int n_in,
                              void* d_out, int out_size, void* d_ws, size_t ws_size,
                              hipStream_t stream) {
  const float* descs = (const float*)d_in[0];
  const float* l_a   = (const float*)d_in[1];
  const float* l_p   = (const float*)d_in[2];
  float* out = (float*)d_out;
  char* ws = (char*)d_ws;

  float* xn  = (float*)(ws + OFF_XN);
  float* pos = (float*)(ws + OFF_POS);
  float* neg = (float*)(ws + OFF_NEG);
  unsigned long long* rowpart = (unsigned long long*)(ws + OFF_ROWPART);
  unsigned long long* colpart = (unsigned long long*)(ws + OFF_COLPART);
  unsigned long long* fin     = (unsigned long long*)(ws + OFF_FIN);
  float* bce = (float*)(ws + OFF_BCE);

  knorm  <<<(6*CNT)/4, 256, 0, stream>>>(descs, xn);
  kdiag  <<<(3*CNT)/4, 256, 0, stream>>>(xn, pos);
  kgemm  <<<dim3(64,64,3), 256, 0, stream>>>(xn, rowpart, colpart);
  kreduce<<<(2*3*CNT)/4, 256, 0, stream>>>(rowpart, colpart, fin);
  kneg   <<<(3*CNT)/4, 256, 0, stream>>>(xn, fin, neg);
  kbce   <<<200, 256, 0, stream>>>(pos, neg, bce);
  kfinal <<<1, 256, 0, stream>>>(pos, neg, bce, l_a, l_p, out);
}

// Round 2
// 373.631 us; speedup vs baseline: 3.8164x; 3.8164x over previous
//
#include <hip/hip_runtime.h>
#include <stdint.h>

#define CNT 8192
#define DIM 128

// ---- workspace layout (bytes) ----
#define OFF_XN      ((size_t)0)                            // 6*CNT*DIM*4 = 25,165,824
#define OFF_POS     ((size_t)6*CNT*DIM*4)                  // 3*CNT floats
#define OFF_NEG     (OFF_POS + (size_t)3*CNT*4)            // 3*CNT floats
#define OFF_ROWPART (OFF_NEG + (size_t)3*CNT*4)            // 3*64*CNT u64
#define OFF_COLPART (OFF_ROWPART + (size_t)3*64*CNT*8)     // 3*64*CNT u64
#define OFF_FIN     (OFF_COLPART + (size_t)3*64*CNT*8)     // 2*3*CNT u64
#define OFF_BCE     (OFF_FIN + (size_t)2*3*CNT*8)          // 200 floats
#define OFF_XNB     (OFF_BCE + (size_t)1024)               // 6*CNT*DIM bf16 = 12.6 MB
// total ~61 MiB

typedef __attribute__((ext_vector_type(8))) short short8;
typedef __attribute__((ext_vector_type(4))) float f32x4;

// row-normalize: one wave per row; writes f32 xn and bf16 xnb
__global__ __launch_bounds__(256) void knorm(const float* __restrict__ in, float* __restrict__ xn,
                                             unsigned int* __restrict__ xnb32){
  const int row  = blockIdx.x*4 + (threadIdx.x>>6);
  const int lane = threadIdx.x & 63;
  const float2 v = *(const float2*)(in + (size_t)row*DIM + lane*2);
  float ss = v.x*v.x + v.y*v.y;
  #pragma unroll
  for (int m=1;m<64;m<<=1) ss += __shfl_xor(ss, m, 64);
  const float n = sqrtf(ss);
  float2 o; o.x = v.x/n; o.y = v.y/n;
  *(float2*)(xn + (size_t)row*DIM + lane*2) = o;
  // bf16 RNE
  unsigned int ux = __float_as_uint(o.x), uy = __float_as_uint(o.y);
  ux = (ux + 0x7FFFu + ((ux>>16)&1u)) >> 16;
  uy = (uy + 0x7FFFu + ((uy>>16)&1u)) >> 16;
  xnb32[(size_t)row*64 + lane] = ux | (uy<<16);
}

__device__ __forceinline__ float wave_dot(const float* __restrict__ a, const float* __restrict__ b, int lane){
  const float2 va = *(const float2*)(a + lane*2);
  const float2 vb = *(const float2*)(b + lane*2);
  float s = va.x*vb.x + va.y*vb.y;
  #pragma unroll
  for (int m=1;m<64;m<<=1) s += __shfl_xor(s, m, 64);
  return s;
}

// positive pair dots (exact f32)
__global__ __launch_bounds__(256) void kdiag(const float* __restrict__ xn, float* __restrict__ pos){
  const int t = blockIdx.x*4 + (threadIdx.x>>6);
  const int lane = threadIdx.x & 63;
  const int p = t >> 13, i = t & (CNT-1);
  const int xo[3] = {0, 2*CNT, 4*CNT};
  const int yo[3] = {CNT, 5*CNT, 3*CNT};
  float d = wave_dot(xn + (size_t)(xo[p]+i)*DIM, xn + (size_t)(yo[p]+i)*DIM, lane);
  if (lane == 0) pos[p*CNT + i] = d;
}

// ---------------- MFMA bf16 GEMM + fused argmin epilogue ----------------
// Ordering: dm = 1/x + eps ascending  <=>  h(x) = (x<0 ? x+4 : x) descending.
// key = ~(bits(h)|0x80000000) ascending; pk = key:32 | idx:32 (min => ref order + lowest-idx ties).
// Diagonal +BIG replicated by x' = x/(1+1e5*x)  (1/x' = 1/x + 1e5), monotone-exact.
__global__ __launch_bounds__(256) void kgemm(const unsigned short* __restrict__ xnb,
    unsigned long long* __restrict__ rowpart, unsigned long long* __restrict__ colpart){
  __shared__ __align__(16) unsigned short Xs[128*128];   // 32 KB
  __shared__ __align__(16) unsigned short Ys[128*128];   // 32 KB
  const int pair = blockIdx.z;
  const int xo3[3] = {0, 2*CNT, 4*CNT};
  const int yo3[3] = {CNT, 5*CNT, 3*CNT};
  const unsigned short* __restrict__ X = xnb + (size_t)xo3[pair]*DIM;
  const unsigned short* __restrict__ Y = xnb + (size_t)yo3[pair]*DIM;
  const int brow = blockIdx.y*128, bcol = blockIdx.x*128;
  const int tid = threadIdx.x, lane = tid & 63, wid = tid >> 6;
  const int wr = wid >> 1, wc = wid & 1;           // 2x2 waves, 64x64 tiles
  const int lrow = lane & 15, kgrp = lane >> 4;

  // ---- stage tiles: global_load_lds (linear LDS dest, pre-swizzled global src) ----
  // LDS layout target: row r, byte b holds global row r byte (b ^ ((r&7)<<4))
  {
    const int nb = lrow * 16;                      // nominal byte within row
    #pragma unroll
    for (int c8 = 0; c8 < 8; ++c8){
      const int c  = wid*8 + c8;                   // 1KB chunk id (4 rows)
      const int rr = c*4 + kgrp;                   // tile row this lane covers
      const int sb = nb ^ ((rr & 7) << 4);
      const unsigned short* gx = X + (size_t)(brow + rr)*DIM + (sb >> 1);
      const unsigned short* gy = Y + (size_t)(bcol + rr)*DIM + (sb >> 1);
      __builtin_amdgcn_global_load_lds((const __attribute__((address_space(1))) void*)gx,
          (__attribute__((address_space(3))) void*)(Xs + c*512), 16, 0, 0);
      __builtin_amdgcn_global_load_lds((const __attribute__((address_space(1))) void*)gy,
          (__attribute__((address_space(3))) void*)(Ys + c*512), 16, 0, 0);
    }
  }
  __syncthreads();

  // ---- MFMA: D = X_tile * Y_tile^T, 16x16x32 frags ----
  f32x4 acc[4][4];
  #pragma unroll
  for (int m=0;m<4;m++)
    #pragma unroll
    for (int n=0;n<4;n++)
      acc[m][n] = (f32x4){0.f,0.f,0.f,0.f};

  const int swz = (lrow & 7) << 4;
  #pragma unroll
  for (int ks = 0; ks < 4; ++ks){
    short8 av[4], bv[4];
    const int kb = (ks*64 + kgrp*16) ^ swz;
    #pragma unroll
    for (int m=0;m<4;m++){
      const int ra = wr*64 + m*16 + lrow;
      const int rb = wc*64 + m*16 + lrow;
      av[m] = *(const short8*)((const char*)Xs + ra*256 + kb);
      bv[m] = *(const short8*)((const char*)Ys + rb*256 + kb);
    }
    #pragma unroll
    for (int m=0;m<4;m++)
      #pragma unroll
      for (int n=0;n<4;n++)
        acc[m][n] = __builtin_amdgcn_mfma_f32_16x16x32_bf16(av[m], bv[n], acc[m][n], 0, 0, 0);
  }

  // ---- diagonal fix (only blocks on the diagonal) ----
  // D element (row = kgrp*4 + r + m*16 + wr*64, col = lrow + n*16 + wc*64)
  if (blockIdx.x == blockIdx.y && wr == wc && kgrp == (lrow >> 2)){
    #pragma unroll
    for (int r=0;r<4;r++)
      if ((lrow & 3) == r){
        #pragma unroll
        for (int m=0;m<4;m++){
          const float x = acc[m][m][r];
          acc[m][m][r] = x / (1.0f + 100000.0f*x);
        }
      }
  }

  // ---- h transform ----
  #pragma unroll
  for (int m=0;m<4;m++)
    #pragma unroll
    for (int n=0;n<4;n++)
      #pragma unroll
      for (int r=0;r<4;r++){
        const float x = acc[m][n][r];
        acc[m][n][r] = (x < 0.0f) ? (x + 4.0f) : x;
      }

  // ---- row candidates: per (m,r), max over this thread's 4 cols ----
  unsigned long long rpk[4][4];
  const int cb = bcol + wc*64 + lrow;
  #pragma unroll
  for (int m=0;m<4;m++)
    #pragma unroll
    for (int r=0;r<4;r++){
      const float h0=acc[m][0][r], h1=acc[m][1][r], h2=acc[m][2][r], h3=acc[m][3][r];
      const float hmax = fmaxf(fmaxf(h0,h1), fmaxf(h2,h3));
      int cand = cb + 48;
      if (h2 == hmax) cand = cb + 32;
      if (h1 == hmax) cand = cb + 16;
      if (h0 == hmax) cand = cb;               // lowest col wins ties
      const unsigned int key = ~(__float_as_uint(hmax) | 0x80000000u);
      rpk[m][r] = ((unsigned long long)key << 32) | (unsigned int)cand;
    }

  // ---- col results: per n, max over 16 in-thread rows + 4 kgrp lanes ----
  unsigned long long cpk[4];
  #pragma unroll
  for (int n=0;n<4;n++){
    float hm = acc[0][n][0];
    #pragma unroll
    for (int m=0;m<4;m++)
      #pragma unroll
      for (int r=0;r<4;r++)
        hm = fmaxf(hm, acc[m][n][r]);
    hm = fmaxf(hm, __shfl_xor(hm, 16, 64));
    hm = fmaxf(hm, __shfl_xor(hm, 32, 64));
    int cand = 0x7FFFFFFF;
    #pragma unroll
    for (int m=3;m>=0;m--)
      #pragma unroll
      for (int r=3;r>=0;r--)
        if (acc[m][n][r] == hm) cand = brow + wr*64 + m*16 + kgrp*4 + r;
    cand = min(cand, __shfl_xor(cand, 16, 64));
    cand = min(cand, __shfl_xor(cand, 32, 64));
    const unsigned int key = ~(__float_as_uint(hm) | 0x80000000u);
    cpk[n] = ((unsigned long long)key << 32) | (unsigned int)cand;
  }

  // ---- LDS transpose for row-min, small buffer for col-min ----
  __syncthreads();                                  // tiles consumed; reuse LDS
  unsigned long long* rowbuf = (unsigned long long*)Xs;   // [128 rows][32 cands], XOR-swizzled
  unsigned long long* colred = (unsigned long long*)Ys;   // [2][128]
  {
    const int cslot = wc*16 + lrow;
    #pragma unroll
    for (int m=0;m<4;m++)
      #pragma unroll
      for (int r=0;r<4;r++){
        const int row = wr*64 + m*16 + kgrp*4 + r;
        const int b = (cslot*8) ^ ((row & 15) << 4);
        *(unsigned long long*)((char*)rowbuf + row*256 + b) = rpk[m][r];
      }
  }
  if (kgrp == 0){
    #pragma unroll
    for (int n=0;n<4;n++)
      colred[wr*128 + wc*64 + n*16 + lrow] = cpk[n];
  }
  __syncthreads();

  if (tid < 128){
    const int row = tid;
    const int sw = (row & 15) << 4;
    unsigned long long best = 0xFFFFFFFFFFFFFFFFull;
    #pragma unroll
    for (int q=0;q<16;q++){
      const unsigned long long* p2 = (const unsigned long long*)((const char*)rowbuf + row*256 + ((q*16) ^ sw));
      const unsigned long long v0 = p2[0], v1 = p2[1];
      best = v0 < best ? v0 : best;
      best = v1 < best ? v1 : best;
    }
    rowpart[((size_t)pair*64 + blockIdx.x)*CNT + (brow + row)] = best;
  } else {
    const int c = tid - 128;
    const unsigned long long a0 = colred[c], a1 = colred[128 + c];
    colpart[((size_t)pair*64 + blockIdx.y)*CNT + (bcol + c)] = a0 < a1 ? a0 : a1;
  }
}

// reduce 64 block-partials -> final row/col min per (pair, index)
__global__ __launch_bounds__(256) void kreduce(const unsigned long long* __restrict__ rowpart,
    const unsigned long long* __restrict__ colpart, unsigned long long* __restrict__ fin){
  const int e = blockIdx.x*4 + (threadIdx.x>>6);   // 0..49151
  const int lane = threadIdx.x & 63;
  const int kind = e / (3*CNT);
  const int rem  = e - kind*(3*CNT);
  const int p = rem >> 13, i = rem & (CNT-1);
  const unsigned long long* src = kind ? colpart : rowpart;
  unsigned long long v = src[((size_t)p*64 + lane)*CNT + i];
  #pragma unroll
  for (int m=1;m<64;m<<=1){
    unsigned long long o = __shfl_xor(v, m, 64);
    v = o < v ? o : v;
  }
  if (lane == 0) fin[(size_t)kind*(3*CNT) + rem] = v;
}

// select hard negative (key compare: smaller key = smaller dm) and compute exact dot
__global__ __launch_bounds__(256) void kneg(const float* __restrict__ xn,
    const unsigned long long* __restrict__ fin, float* __restrict__ neg){
  const int e = blockIdx.x*4 + (threadIdx.x>>6);   // 0..24575
  const int lane = threadIdx.x & 63;
  const int p = e >> 13, i = e & (CNT-1);
  const int xo[3] = {0, 2*CNT, 4*CNT};
  const int yo[3] = {CNT, 5*CNT, 3*CNT};
  const unsigned long long rv = fin[p*CNT + i];
  const unsigned long long cv = fin[3*CNT + p*CNT + i];
  const unsigned int rkey = (unsigned int)(rv >> 32), ckey = (unsigned int)(cv >> 32);
  int orow;
  if (rkey < ckey) orow = yo[p] + (int)(rv & 0xFFFFFFFFull);   // row branch -> Y row
  else             orow = xo[p] + (int)(cv & 0xFFFFFFFFull);   // col branch -> X row
  float d = wave_dot(xn + (size_t)(xo[p]+i)*DIM, xn + (size_t)orow*DIM, lane);
  if (lane == 0) neg[p*CNT + i] = d;
}

// per-alpha BCE (200 blocks). three passes: mean, std(ddof=1), bce.
__global__ __launch_bounds__(256) void kbce(const float* __restrict__ pos, const float* __restrict__ neg,
    float* __restrict__ bce){
  const int kk = blockIdx.x;
  const float a = -1.0f + 0.01f*(float)kk;
  const int tid = threadIdx.x;
  __shared__ float red[4];

  float s = 0.0f;
  for (int idx = tid; idx < 6*CNT; idx += 256){
    const float d = (idx < 3*CNT) ? pos[idx] : neg[idx - 3*CNT];
    const float om = 1.0f - d;
    const float dist = a*om + (1.0f - a)*sqrtf(2.0f*om + 1e-12f);
    s += dist;
  }
  #pragma unroll
  for (int m=1;m<64;m<<=1) s += __shfl_xor(s, m, 64);
  if ((tid & 63) == 0) red[tid>>6] = s;
  __syncthreads();
  const float mean = (red[0]+red[1]+red[2]+red[3]) / 49152.0f;
  __syncthreads();

  float ss = 0.0f;
  for (int idx = tid; idx < 6*CNT; idx += 256){
    const float d = (idx < 3*CNT) ? pos[idx] : neg[idx - 3*CNT];
    const float om = 1.0f - d;
    const float dist = a*om + (1.0f - a)*sqrtf(2.0f*om + 1e-12f);
    const float dd = dist - mean;
    ss += dd*dd;
  }
  #pragma unroll
  for (int m=1;m<64;m<<=1) ss += __shfl_xor(ss, m, 64);
  if ((tid & 63) == 0) red[tid>>6] = ss;
  __syncthreads();
  const float stdv = sqrtf((red[0]+red[1]+red[2]+red[3]) / 49151.0f);
  __syncthreads();

  float bs = 0.0f;
  for (int idx = tid; idx < 6*CNT; idx += 256){
    const float d = (idx < 3*CNT) ? pos[idx] : neg[idx - 3*CNT];
    const float om = 1.0f - d;
    const float dist = a*om + (1.0f - a)*sqrtf(2.0f*om + 1e-12f);
    const float pr = 1.0f/(1.0f + expf((dist - mean)/stdv));   // sigmoid(-(d-mean)/std)
    bs += (idx < 3*CNT) ? -logf(pr) : -logf(1.0f - pr);
  }
  #pragma unroll
  for (int m=1;m<64;m<<=1) bs += __shfl_xor(bs, m, 64);
  if ((tid & 63) == 0) red[tid>>6] = bs;
  __syncthreads();
  if (tid == 0) bce[kk] = (red[0]+red[1]+red[2]+red[3]) / 49152.0f;
}

// argmin(bce) -> alpha; losses, mask ratio, l_mean; write 8 outputs
__global__ __launch_bounds__(256) void kfinal(const float* __restrict__ pos, const float* __restrict__ neg,
    const float* __restrict__ bce, const float* __restrict__ l_a_adv, const float* __restrict__ l_p_adv,
    float* __restrict__ out){
  __shared__ float sal[2];
  __shared__ float red[4];
  const int tid = threadIdx.x;
  if (tid == 0){
    float best = bce[0]; int bk = 0;
    for (int k=1;k<200;k++){
      const float v = bce[k];
      if (v < best){ best = v; bk = k; }
    }
    const float aopt = -1.0f + 0.01f*(float)bk;
    sal[0] = aopt;              // alpha_opt
    sal[1] = aopt * 0.005f;     // alpha = 0*0.995 + aopt*(1-0.995)
  }
  __syncthreads();
  const float alpha = sal[1];

  float sc=0.f, sar=0.f, saa=0.f, sm=0.f, sla=0.f, slp=0.f;
  for (int i = tid; i < CNT; i += 256){
    const float pap = pos[i],        nap = neg[i];
    const float par = pos[CNT+i],    nar = neg[CNT+i];
    const float paa = pos[2*CNT+i],  naa = neg[2*CNT+i];
    const float cp = fminf(fmaxf(pap, -1.0f), 1.0f);
    const float cn = fminf(fmaxf(nap, -1.0f), 1.0f);
    const float m = (0.36f + acosf(cp) - acosf(cn) > 0.0f) ? 1.0f : 0.0f;
    #define DDIST(d) (alpha*(1.0f-(d)) + (1.0f-alpha)*sqrtf(2.0f*(1.0f-(d)) + 1e-12f))
    sc  += (DDIST(pap) - DDIST(nap)) * m;
    sar += (l_p_adv[i]*DDIST(par) - DDIST(nar)) * m;
    saa += (l_a_adv[i]*DDIST(paa) - DDIST(naa)) * m;
    sm  += m;
    sla += l_a_adv[i];
    slp += l_p_adv[i];
  }
  float vals[6] = {sc, sar, saa, sm, sla, slp};
  float tot[6];
  for (int v=0; v<6; v++){
    float x = vals[v];
    #pragma unroll
    for (int m2=1;m2<64;m2<<=1) x += __shfl_xor(x, m2, 64);
    __syncthreads();
    if ((tid & 63) == 0) red[tid>>6] = x;
    __syncthreads();
    tot[v] = red[0]+red[1]+red[2]+red[3];
  }
  if (tid == 0){
    const float lc  = tot[0] / (float)CNT;
    const float lar = tot[1] / (float)CNT;
    const float laa = tot[2] / (float)CNT;
    out[0] = (lc + lar + laa) / 3.0f;
    out[1] = lc;
    out[2] = lar;
    out[3] = laa;
    out[4] = (tot[4]/(float)CNT + tot[5]/(float)CNT) * 0.5f;
    out[5] = sal[1];
    out[6] = sal[0];
    out[7] = tot[3] / (float)CNT;
  }
}

extern "C" void kernel_launch(void* const* d_in, const int* in_sizes, int n_in,
                              void* d_out, int out_size, void* d_ws, size_t ws_size,
                              hipStream_t stream) {
  const float* descs = (const float*)d_in[0];
  const float* l_a   = (const float*)d_in[1];
  const float* l_p   = (const float*)d_in[2];
  float* out = (float*)d_out;
  char* ws = (char*)d_ws;

  float* xn  = (float*)(ws + OFF_XN);
  float* pos = (float*)(ws + OFF_POS);
  float* neg = (float*)(ws + OFF_NEG);
  unsigned long long* rowpart = (unsigned long long*)(ws + OFF_ROWPART);
  unsigned long long* colpart = (unsigned long long*)(ws + OFF_COLPART);
  unsigned long long* fin     = (unsigned long long*)(ws + OFF_FIN);
  float* bce = (float*)(ws + OFF_BCE);
  unsigned int* xnb32 = (unsigned int*)(ws + OFF_XNB);
  const unsigned short* xnb = (const unsigned short*)(ws + OFF_XNB);

  knorm  <<<(6*CNT)/4, 256, 0, stream>>>(descs, xn, xnb32);
  kdiag  <<<(3*CNT)/4, 256, 0, stream>>>(xn, pos);
  kgemm  <<<dim3(64,64,3), 256, 0, stream>>>(xnb, rowpart, colpart);
  kreduce<<<(2*3*CNT)/4, 256, 0, stream>>>(rowpart, colpart, fin);
  kneg   <<<(3*CNT)/4, 256, 0, stream>>>(xn, fin, neg);
  kbce   <<<200, 256, 0, stream>>>(pos, neg, bce);
  kfinal <<<1, 256, 0, stream>>>(pos, neg, bce, l_a, l_p, out);
}

// Round 3
// 305.556 us; speedup vs baseline: 4.6667x; 1.2228x over previous
//
#include <hip/hip_runtime.h>
#include <stdint.h>

#define CNT 8192
#define DIM 128

// ---- workspace layout (bytes) ----
#define OFF_XN      ((size_t)0)                            // 6*CNT*DIM*4 = 25,165,824
#define OFF_POS     ((size_t)6*CNT*DIM*4)                  // 3*CNT floats
#define OFF_NEG     (OFF_POS + (size_t)3*CNT*4)            // 3*CNT floats
#define OFF_ROWPART (OFF_NEG + (size_t)3*CNT*4)            // 3*64*CNT u64
#define OFF_COLPART (OFF_ROWPART + (size_t)3*64*CNT*8)     // 3*64*CNT u64
#define OFF_FIN     (OFF_COLPART + (size_t)3*64*CNT*8)     // 2*3*CNT u64
#define OFF_U       (OFF_FIN + (size_t)2*3*CNT*8)          // 6*CNT floats
#define OFF_V       (OFF_U + (size_t)6*CNT*4)              // 6*CNT floats
#define OFF_MPART   (OFF_V + (size_t)6*CNT*4)              // 192*2 floats
#define OFF_AMEAN   (OFF_MPART + (size_t)2048)             // 200 floats
#define OFF_AISTD   (OFF_AMEAN + (size_t)1024)             // 200 floats
#define OFF_PSUM    (OFF_AISTD + (size_t)1024)             // 1600 floats
#define OFF_XNB     (OFF_PSUM + (size_t)8192)              // 6*CNT*DIM bf16 = 12.6 MB
// total ~64 MiB

typedef __attribute__((ext_vector_type(8))) short short8;
typedef __attribute__((ext_vector_type(4))) float f32x4;

__device__ __forceinline__ float block_sum(float x, float* red, int tid){
  #pragma unroll
  for (int m=1;m<64;m<<=1) x += __shfl_xor(x, m, 64);
  if ((tid & 63) == 0) red[tid>>6] = x;
  __syncthreads();
  const float r = red[0]+red[1]+red[2]+red[3];
  __syncthreads();
  return r;
}

// row-normalize: one wave per row; writes f32 xn and bf16 xnb
__global__ __launch_bounds__(256) void knorm(const float* __restrict__ in, float* __restrict__ xn,
                                             unsigned int* __restrict__ xnb32){
  const int row  = blockIdx.x*4 + (threadIdx.x>>6);
  const int lane = threadIdx.x & 63;
  const float2 v = *(const float2*)(in + (size_t)row*DIM + lane*2);
  float ss = v.x*v.x + v.y*v.y;
  #pragma unroll
  for (int m=1;m<64;m<<=1) ss += __shfl_xor(ss, m, 64);
  const float n = sqrtf(ss);
  float2 o; o.x = v.x/n; o.y = v.y/n;
  *(float2*)(xn + (size_t)row*DIM + lane*2) = o;
  unsigned int ux = __float_as_uint(o.x), uy = __float_as_uint(o.y);
  ux = (ux + 0x7FFFu + ((ux>>16)&1u)) >> 16;
  uy = (uy + 0x7FFFu + ((uy>>16)&1u)) >> 16;
  xnb32[(size_t)row*64 + lane] = ux | (uy<<16);
}

__device__ __forceinline__ float wave_dot(const float* __restrict__ a, const float* __restrict__ b, int lane){
  const float2 va = *(const float2*)(a + lane*2);
  const float2 vb = *(const float2*)(b + lane*2);
  float s = va.x*vb.x + va.y*vb.y;
  #pragma unroll
  for (int m=1;m<64;m<<=1) s += __shfl_xor(s, m, 64);
  return s;
}

// positive pair dots (exact f32)
__global__ __launch_bounds__(256) void kdiag(const float* __restrict__ xn, float* __restrict__ pos){
  const int t = blockIdx.x*4 + (threadIdx.x>>6);
  const int lane = threadIdx.x & 63;
  const int p = t >> 13, i = t & (CNT-1);
  const int xo[3] = {0, 2*CNT, 4*CNT};
  const int yo[3] = {CNT, 5*CNT, 3*CNT};
  float d = wave_dot(xn + (size_t)(xo[p]+i)*DIM, xn + (size_t)(yo[p]+i)*DIM, lane);
  if (lane == 0) pos[p*CNT + i] = d;
}

// ---------------- MFMA bf16 GEMM + fused argmin epilogue ----------------
__global__ __launch_bounds__(256) void kgemm(const unsigned short* __restrict__ xnb,
    unsigned long long* __restrict__ rowpart, unsigned long long* __restrict__ colpart){
  __shared__ __align__(16) unsigned short Xs[128*128];   // 32 KB
  __shared__ __align__(16) unsigned short Ys[128*128];   // 32 KB
  const int pair = blockIdx.z;
  const int xo3[3] = {0, 2*CNT, 4*CNT};
  const int yo3[3] = {CNT, 5*CNT, 3*CNT};
  const unsigned short* __restrict__ X = xnb + (size_t)xo3[pair]*DIM;
  const unsigned short* __restrict__ Y = xnb + (size_t)yo3[pair]*DIM;
  const int brow = blockIdx.y*128, bcol = blockIdx.x*128;
  const int tid = threadIdx.x, lane = tid & 63, wid = tid >> 6;
  const int wr = wid >> 1, wc = wid & 1;           // 2x2 waves, 64x64 tiles
  const int lrow = lane & 15, kgrp = lane >> 4;

  {
    const int nb = lrow * 16;
    #pragma unroll
    for (int c8 = 0; c8 < 8; ++c8){
      const int c  = wid*8 + c8;
      const int rr = c*4 + kgrp;
      const int sb = nb ^ ((rr & 7) << 4);
      const unsigned short* gx = X + (size_t)(brow + rr)*DIM + (sb >> 1);
      const unsigned short* gy = Y + (size_t)(bcol + rr)*DIM + (sb >> 1);
      __builtin_amdgcn_global_load_lds((const __attribute__((address_space(1))) void*)gx,
          (__attribute__((address_space(3))) void*)(Xs + c*512), 16, 0, 0);
      __builtin_amdgcn_global_load_lds((const __attribute__((address_space(1))) void*)gy,
          (__attribute__((address_space(3))) void*)(Ys + c*512), 16, 0, 0);
    }
  }
  __syncthreads();

  f32x4 acc[4][4];
  #pragma unroll
  for (int m=0;m<4;m++)
    #pragma unroll
    for (int n=0;n<4;n++)
      acc[m][n] = (f32x4){0.f,0.f,0.f,0.f};

  const int swz = (lrow & 7) << 4;
  #pragma unroll
  for (int ks = 0; ks < 4; ++ks){
    short8 av[4], bv[4];
    const int kb = (ks*64 + kgrp*16) ^ swz;
    #pragma unroll
    for (int m=0;m<4;m++){
      const int ra = wr*64 + m*16 + lrow;
      const int rb = wc*64 + m*16 + lrow;
      av[m] = *(const short8*)((const char*)Xs + ra*256 + kb);
      bv[m] = *(const short8*)((const char*)Ys + rb*256 + kb);
    }
    #pragma unroll
    for (int m=0;m<4;m++)
      #pragma unroll
      for (int n=0;n<4;n++)
        acc[m][n] = __builtin_amdgcn_mfma_f32_16x16x32_bf16(av[m], bv[n], acc[m][n], 0, 0, 0);
  }

  if (blockIdx.x == blockIdx.y && wr == wc && kgrp == (lrow >> 2)){
    #pragma unroll
    for (int r=0;r<4;r++)
      if ((lrow & 3) == r){
        #pragma unroll
        for (int m=0;m<4;m++){
          const float x = acc[m][m][r];
          acc[m][m][r] = x / (1.0f + 100000.0f*x);
        }
      }
  }

  #pragma unroll
  for (int m=0;m<4;m++)
    #pragma unroll
    for (int n=0;n<4;n++)
      #pragma unroll
      for (int r=0;r<4;r++){
        const float x = acc[m][n][r];
        acc[m][n][r] = (x < 0.0f) ? (x + 4.0f) : x;
      }

  unsigned long long rpk[4][4];
  const int cb = bcol + wc*64 + lrow;
  #pragma unroll
  for (int m=0;m<4;m++)
    #pragma unroll
    for (int r=0;r<4;r++){
      const float h0=acc[m][0][r], h1=acc[m][1][r], h2=acc[m][2][r], h3=acc[m][3][r];
      const float hmax = fmaxf(fmaxf(h0,h1), fmaxf(h2,h3));
      int cand = cb + 48;
      if (h2 == hmax) cand = cb + 32;
      if (h1 == hmax) cand = cb + 16;
      if (h0 == hmax) cand = cb;
      const unsigned int key = ~(__float_as_uint(hmax) | 0x80000000u);
      rpk[m][r] = ((unsigned long long)key << 32) | (unsigned int)cand;
    }

  unsigned long long cpk[4];
  #pragma unroll
  for (int n=0;n<4;n++){
    float hm = acc[0][n][0];
    #pragma unroll
    for (int m=0;m<4;m++)
      #pragma unroll
      for (int r=0;r<4;r++)
        hm = fmaxf(hm, acc[m][n][r]);
    hm = fmaxf(hm, __shfl_xor(hm, 16, 64));
    hm = fmaxf(hm, __shfl_xor(hm, 32, 64));
    int cand = 0x7FFFFFFF;
    #pragma unroll
    for (int m=3;m>=0;m--)
      #pragma unroll
      for (int r=3;r>=0;r--)
        if (acc[m][n][r] == hm) cand = brow + wr*64 + m*16 + kgrp*4 + r;
    cand = min(cand, __shfl_xor(cand, 16, 64));
    cand = min(cand, __shfl_xor(cand, 32, 64));
    const unsigned int key = ~(__float_as_uint(hm) | 0x80000000u);
    cpk[n] = ((unsigned long long)key << 32) | (unsigned int)cand;
  }

  __syncthreads();
  unsigned long long* rowbuf = (unsigned long long*)Xs;
  unsigned long long* colred = (unsigned long long*)Ys;
  {
    const int cslot = wc*16 + lrow;
    #pragma unroll
    for (int m=0;m<4;m++)
      #pragma unroll
      for (int r=0;r<4;r++){
        const int row = wr*64 + m*16 + kgrp*4 + r;
        const int b = (cslot*8) ^ ((row & 15) << 4);
        *(unsigned long long*)((char*)rowbuf + row*256 + b) = rpk[m][r];
      }
  }
  if (kgrp == 0){
    #pragma unroll
    for (int n=0;n<4;n++)
      colred[wr*128 + wc*64 + n*16 + lrow] = cpk[n];
  }
  __syncthreads();

  if (tid < 128){
    const int row = tid;
    const int sw = (row & 15) << 4;
    unsigned long long best = 0xFFFFFFFFFFFFFFFFull;
    #pragma unroll
    for (int q=0;q<16;q++){
      const unsigned long long* p2 = (const unsigned long long*)((const char*)rowbuf + row*256 + ((q*16) ^ sw));
      const unsigned long long v0 = p2[0], v1 = p2[1];
      best = v0 < best ? v0 : best;
      best = v1 < best ? v1 : best;
    }
    rowpart[((size_t)pair*64 + blockIdx.x)*CNT + (brow + row)] = best;
  } else {
    const int c = tid - 128;
    const unsigned long long a0 = colred[c], a1 = colred[128 + c];
    colpart[((size_t)pair*64 + blockIdx.y)*CNT + (bcol + c)] = a0 < a1 ? a0 : a1;
  }
}

// reduce 64 block-partials -> final row/col min per (pair, index)
__global__ __launch_bounds__(256) void kreduce(const unsigned long long* __restrict__ rowpart,
    const unsigned long long* __restrict__ colpart, unsigned long long* __restrict__ fin){
  const int e = blockIdx.x*4 + (threadIdx.x>>6);
  const int lane = threadIdx.x & 63;
  const int kind = e / (3*CNT);
  const int rem  = e - kind*(3*CNT);
  const int p = rem >> 13, i = rem & (CNT-1);
  const unsigned long long* src = kind ? colpart : rowpart;
  unsigned long long v = src[((size_t)p*64 + lane)*CNT + i];
  #pragma unroll
  for (int m=1;m<64;m<<=1){
    unsigned long long o = __shfl_xor(v, m, 64);
    v = o < v ? o : v;
  }
  if (lane == 0) fin[(size_t)kind*(3*CNT) + rem] = v;
}

// select hard negative and compute exact dot
__global__ __launch_bounds__(256) void kneg(const float* __restrict__ xn,
    const unsigned long long* __restrict__ fin, float* __restrict__ neg){
  const int e = blockIdx.x*4 + (threadIdx.x>>6);
  const int lane = threadIdx.x & 63;
  const int p = e >> 13, i = e & (CNT-1);
  const int xo[3] = {0, 2*CNT, 4*CNT};
  const int yo[3] = {CNT, 5*CNT, 3*CNT};
  const unsigned long long rv = fin[p*CNT + i];
  const unsigned long long cv = fin[3*CNT + p*CNT + i];
  const unsigned int rkey = (unsigned int)(rv >> 32), ckey = (unsigned int)(cv >> 32);
  int orow;
  if (rkey < ckey) orow = yo[p] + (int)(rv & 0xFFFFFFFFull);
  else             orow = xo[p] + (int)(cv & 0xFFFFFFFFull);
  float d = wave_dot(xn + (size_t)(xo[p]+i)*DIM, xn + (size_t)orow*DIM, lane);
  if (lane == 0) neg[p*CNT + i] = d;
}

// ---- alpha sweep, restructured: dist(a,i) = a*u_i + v_i ----
// kuv: compute u,v per element + block partial sums of u,v
__global__ __launch_bounds__(256) void kuv(const float* __restrict__ pos, const float* __restrict__ neg,
    float* __restrict__ u, float* __restrict__ v, float* __restrict__ mpart){
  __shared__ float red[4];
  const int tid = threadIdx.x;
  const int idx = blockIdx.x*256 + tid;
  const float d = (idx < 3*CNT) ? pos[idx] : neg[idx - 3*CNT];
  const float om = 1.0f - d;
  const float sq = sqrtf(2.0f*om + 1e-12f);
  const float uu = om - sq;
  u[idx] = uu;
  v[idx] = sq;
  const float su = block_sum(uu, red, tid);
  const float sv = block_sum(sq, red, tid);
  if (tid == 0){
    mpart[blockIdx.x*2 + 0] = su;
    mpart[blockIdx.x*2 + 1] = sv;
  }
}

// kmom: finalize means, compute centered moments (two-pass), per-alpha mean & inv_std
__global__ __launch_bounds__(256) void kmom(const float* __restrict__ u, const float* __restrict__ v,
    const float* __restrict__ mpart, float* __restrict__ amean, float* __restrict__ aistd){
  __shared__ float red[4];
  __shared__ float smu[2];
  __shared__ float smom[3];
  const int tid = threadIdx.x;
  float su = 0.f, sv = 0.f;
  for (int i = tid; i < 192; i += 256){ su += mpart[2*i]; sv += mpart[2*i+1]; }
  su = block_sum(su, red, tid);
  sv = block_sum(sv, red, tid);
  if (tid == 0){ smu[0] = su / 49152.0f; smu[1] = sv / 49152.0f; }
  __syncthreads();
  const float mu_u = smu[0], mu_v = smu[1];
  float suu = 0.f, suv = 0.f, svv = 0.f;
  for (int i = tid; i < 6*CNT; i += 256){
    const float cu = u[i] - mu_u;
    const float cv = v[i] - mu_v;
    suu = fmaf(cu, cu, suu);
    suv = fmaf(cu, cv, suv);
    svv = fmaf(cv, cv, svv);
  }
  suu = block_sum(suu, red, tid);
  suv = block_sum(suv, red, tid);
  svv = block_sum(svv, red, tid);
  if (tid == 0){ smom[0] = suu; smom[1] = suv; smom[2] = svv; }
  __syncthreads();
  if (tid < 200){
    const float a = -1.0f + 0.01f*(float)tid;
    amean[tid] = a*mu_u + mu_v;
    const float var = (a*a*smom[0] + 2.0f*a*smom[1] + smom[2]) / 49151.0f;
    aistd[tid] = 1.0f / sqrtf(var);
  }
}

// kbce: grid (200 alphas x 8 chunks); partial softplus sums
__global__ __launch_bounds__(256) void kbce(const float* __restrict__ u, const float* __restrict__ v,
    const float* __restrict__ amean, const float* __restrict__ aistd, float* __restrict__ psum){
  __shared__ float red[4];
  const int tid = threadIdx.x;
  const int a = blockIdx.x >> 3, c = blockIdx.x & 7;
  const float av = -1.0f + 0.01f*(float)a;
  const float mean = amean[a], istd = aistd[a];
  const int base = c*6144;
  float s = 0.0f;
  #pragma unroll 4
  for (int k = 0; k < 24; ++k){
    const int idx = base + k*256 + tid;
    const float z = (fmaf(av, u[idx], v[idx]) - mean) * istd;
    const float zz = (idx < 3*CNT) ? z : -z;          // label=1 -> softplus(z); label=0 -> softplus(-z)
    s += fmaxf(zz, 0.0f) + log1pf(expf(-fabsf(zz)));
  }
  s = block_sum(s, red, tid);
  if (tid == 0) psum[blockIdx.x] = s;
}

// argmin(bce) -> alpha; losses, mask ratio, l_mean; write 8 outputs
__global__ __launch_bounds__(256) void kfinal(const float* __restrict__ pos, const float* __restrict__ neg,
    const float* __restrict__ psum, const float* __restrict__ l_a_adv, const float* __restrict__ l_p_adv,
    float* __restrict__ out){
  __shared__ float sbce[200];
  __shared__ float sal[2];
  __shared__ float red[4];
  const int tid = threadIdx.x;
  if (tid < 200){
    float s = 0.f;
    #pragma unroll
    for (int c=0;c<8;c++) s += psum[tid*8 + c];
    sbce[tid] = s;                       // positive scale of bce; argmin-invariant
  }
  __syncthreads();
  if (tid == 0){
    float best = sbce[0]; int bk = 0;
    for (int k=1;k<200;k++){
      const float vv = sbce[k];
      if (vv < best){ best = vv; bk = k; }
    }
    const float aopt = -1.0f + 0.01f*(float)bk;
    sal[0] = aopt;
    sal[1] = aopt * 0.005f;
  }
  __syncthreads();
  const float alpha = sal[1];

  float sc=0.f, sar=0.f, saa=0.f, sm=0.f, sla=0.f, slp=0.f;
  for (int i = tid; i < CNT; i += 256){
    const float pap = pos[i],        nap = neg[i];
    const float par = pos[CNT+i],    nar = neg[CNT+i];
    const float paa = pos[2*CNT+i],  naa = neg[2*CNT+i];
    const float cp = fminf(fmaxf(pap, -1.0f), 1.0f);
    const float cn = fminf(fmaxf(nap, -1.0f), 1.0f);
    const float m = (0.36f + acosf(cp) - acosf(cn) > 0.0f) ? 1.0f : 0.0f;
    #define DDIST(d) (alpha*(1.0f-(d)) + (1.0f-alpha)*sqrtf(2.0f*(1.0f-(d)) + 1e-12f))
    sc  += (DDIST(pap) - DDIST(nap)) * m;
    sar += (l_p_adv[i]*DDIST(par) - DDIST(nar)) * m;
    saa += (l_a_adv[i]*DDIST(paa) - DDIST(naa)) * m;
    sm  += m;
    sla += l_a_adv[i];
    slp += l_p_adv[i];
  }
  float vals[6] = {sc, sar, saa, sm, sla, slp};
  float tot[6];
  for (int vv=0; vv<6; vv++){
    tot[vv] = block_sum(vals[vv], red, tid);
  }
  if (tid == 0){
    const float lc  = tot[0] / (float)CNT;
    const float lar = tot[1] / (float)CNT;
    const float laa = tot[2] / (float)CNT;
    out[0] = (lc + lar + laa) / 3.0f;
    out[1] = lc;
    out[2] = lar;
    out[3] = laa;
    out[4] = (tot[4]/(float)CNT + tot[5]/(float)CNT) * 0.5f;
    out[5] = sal[1];
    out[6] = sal[0];
    out[7] = tot[3] / (float)CNT;
  }
}

extern "C" void kernel_launch(void* const* d_in, const int* in_sizes, int n_in,
                              void* d_out, int out_size, void* d_ws, size_t ws_size,
                              hipStream_t stream) {
  const float* descs = (const float*)d_in[0];
  const float* l_a   = (const float*)d_in[1];
  const float* l_p   = (const float*)d_in[2];
  float* out = (float*)d_out;
  char* ws = (char*)d_ws;

  float* xn  = (float*)(ws + OFF_XN);
  float* pos = (float*)(ws + OFF_POS);
  float* neg = (float*)(ws + OFF_NEG);
  unsigned long long* rowpart = (unsigned long long*)(ws + OFF_ROWPART);
  unsigned long long* colpart = (unsigned long long*)(ws + OFF_COLPART);
  unsigned long long* fin     = (unsigned long long*)(ws + OFF_FIN);
  float* u     = (float*)(ws + OFF_U);
  float* v     = (float*)(ws + OFF_V);
  float* mpart = (float*)(ws + OFF_MPART);
  float* amean = (float*)(ws + OFF_AMEAN);
  float* aistd = (float*)(ws + OFF_AISTD);
  float* psum  = (float*)(ws + OFF_PSUM);
  unsigned int* xnb32 = (unsigned int*)(ws + OFF_XNB);
  const unsigned short* xnb = (const unsigned short*)(ws + OFF_XNB);

  knorm  <<<(6*CNT)/4, 256, 0, stream>>>(descs, xn, xnb32);
  kdiag  <<<(3*CNT)/4, 256, 0, stream>>>(xn, pos);
  kgemm  <<<dim3(64,64,3), 256, 0, stream>>>(xnb, rowpart, colpart);
  kreduce<<<(2*3*CNT)/4, 256, 0, stream>>>(rowpart, colpart, fin);
  kneg   <<<(3*CNT)/4, 256, 0, stream>>>(xn, fin, neg);
  kuv    <<<192, 256, 0, stream>>>(pos, neg, u, v, mpart);
  kmom   <<<1, 256, 0, stream>>>(u, v, mpart, amean, aistd);
  kbce   <<<1600, 256, 0, stream>>>(u, v, amean, aistd, psum);
  kfinal <<<1, 256, 0, stream>>>(pos, neg, psum, l_a, l_p, out);
}

// Round 4
// 217.798 us; speedup vs baseline: 6.5470x; 1.4029x over previous
//
#include <hip/hip_runtime.h>
#include <stdint.h>

#define CNT 8192
#define DIM 128

typedef unsigned long long u64;
typedef unsigned int u32;

// ---- workspace layout (bytes) ----
#define OFF_XN      ((size_t)0)                            // 6*CNT*DIM*4
#define OFF_POS     ((size_t)6*CNT*DIM*4)                  // 3*CNT floats
#define OFF_NEG     (OFF_POS + (size_t)3*CNT*4)            // 3*CNT floats
#define OFF_ROWPART (OFF_NEG + (size_t)3*CNT*4)            // 3*64*CNT u64
#define OFF_COLPART (OFF_ROWPART + (size_t)3*64*CNT*8)     // 3*64*CNT u64
#define OFF_U       (OFF_COLPART + (size_t)3*64*CNT*8)     // 6*CNT floats
#define OFF_V       (OFF_U + (size_t)6*CNT*4)              // 6*CNT floats
#define OFF_MPART   (OFF_V + (size_t)6*CNT*4)              // 192*5 floats
#define OFF_AMEAN   (OFF_MPART + (size_t)4096)             // 200 floats
#define OFF_AISTD   (OFF_AMEAN + (size_t)1024)             // 200 floats
#define OFF_PSUM    (OFF_AISTD + (size_t)1024)             // 1600 floats
#define OFF_XNB     (OFF_PSUM + (size_t)8192)              // 6*CNT*DIM bf16

typedef __attribute__((ext_vector_type(8))) short short8;
typedef __attribute__((ext_vector_type(4))) float f32x4;

__device__ __forceinline__ float block_sum(float x, float* red, int tid){
  #pragma unroll
  for (int m=1;m<64;m<<=1) x += __shfl_xor(x, m, 64);
  if ((tid & 63) == 0) red[tid>>6] = x;
  __syncthreads();
  const float r = red[0]+red[1]+red[2]+red[3];
  __syncthreads();
  return r;
}

// row-normalize: f32 xn; bf16 xnb with A-side (even segments) pre-scaled by 0.25
__global__ __launch_bounds__(256) void knorm(const float* __restrict__ in, float* __restrict__ xn,
                                             unsigned int* __restrict__ xnb32){
  const int row  = blockIdx.x*4 + (threadIdx.x>>6);
  const int lane = threadIdx.x & 63;
  const float2 v = *(const float2*)(in + (size_t)row*DIM + lane*2);
  float ss = v.x*v.x + v.y*v.y;
  #pragma unroll
  for (int m=1;m<64;m<<=1) ss += __shfl_xor(ss, m, 64);
  const float n = sqrtf(ss);
  float2 o; o.x = v.x/n; o.y = v.y/n;
  *(float2*)(xn + (size_t)row*DIM + lane*2) = o;
  const float sc = (row & CNT) ? 1.0f : 0.25f;   // segments 0,2,4 (A-side) scaled
  unsigned int ux = __float_as_uint(o.x*sc), uy = __float_as_uint(o.y*sc);
  ux = (ux + 0x7FFFu + ((ux>>16)&1u)) >> 16;
  uy = (uy + 0x7FFFu + ((uy>>16)&1u)) >> 16;
  xnb32[(size_t)row*64 + lane] = ux | (uy<<16);
}

__device__ __forceinline__ float wave_dot(const float* __restrict__ a, const float* __restrict__ b, int lane){
  const float2 va = *(const float2*)(a + lane*2);
  const float2 vb = *(const float2*)(b + lane*2);
  float s = va.x*vb.x + va.y*vb.y;
  #pragma unroll
  for (int m=1;m<64;m<<=1) s += __shfl_xor(s, m, 64);
  return s;
}

// positive pair dots (exact f32)
__global__ __launch_bounds__(256) void kdiag(const float* __restrict__ xn, float* __restrict__ pos){
  const int t = blockIdx.x*4 + (threadIdx.x>>6);
  const int lane = threadIdx.x & 63;
  const int p = t >> 13, i = t & (CNT-1);
  const int xo[3] = {0, 2*CNT, 4*CNT};
  const int yo[3] = {CNT, 5*CNT, 3*CNT};
  float d = wave_dot(xn + (size_t)(xo[p]+i)*DIM, xn + (size_t)(yo[p]+i)*DIM, lane);
  if (lane == 0) pos[p*CNT + i] = d;
}

// ---------------- MFMA bf16 GEMM + fract-key argmin epilogue ----------------
// acc = dot/4 (A pre-scaled). key = fract(acc): max key == min dm (dm = 1/dot + eps).
// Row pack: [key:25][~col7:7]; Col pack: [key:26][~row6:6]. u32 max == argmax + lowest-index ties.
__global__ __launch_bounds__(256) void kgemm(const unsigned short* __restrict__ xnb,
    u64* __restrict__ rowpart, u64* __restrict__ colpart){
  __shared__ __align__(16) unsigned short Xs[128*128];   // 32 KB
  __shared__ __align__(16) unsigned short Ys[128*128];   // 32 KB
  const int pair = blockIdx.z;
  const int xo3[3] = {0, 2*CNT, 4*CNT};
  const int yo3[3] = {CNT, 5*CNT, 3*CNT};
  const unsigned short* __restrict__ X = xnb + (size_t)xo3[pair]*DIM;
  const unsigned short* __restrict__ Y = xnb + (size_t)yo3[pair]*DIM;
  const int brow = blockIdx.y*128, bcol = blockIdx.x*128;
  const int tid = threadIdx.x, lane = tid & 63, wid = tid >> 6;
  const int wr = wid >> 1, wc = wid & 1;           // 2x2 waves, 64x64 tiles
  const int lrow = lane & 15, kgrp = lane >> 4;

  // stage tiles (linear LDS dest, pre-swizzled global src)
  {
    const int nb = lrow * 16;
    #pragma unroll
    for (int c8 = 0; c8 < 8; ++c8){
      const int c  = wid*8 + c8;
      const int rr = c*4 + kgrp;
      const int sb = nb ^ ((rr & 7) << 4);
      const unsigned short* gx = X + (size_t)(brow + rr)*DIM + (sb >> 1);
      const unsigned short* gy = Y + (size_t)(bcol + rr)*DIM + (sb >> 1);
      __builtin_amdgcn_global_load_lds((const __attribute__((address_space(1))) void*)gx,
          (__attribute__((address_space(3))) void*)(Xs + c*512), 16, 0, 0);
      __builtin_amdgcn_global_load_lds((const __attribute__((address_space(1))) void*)gy,
          (__attribute__((address_space(3))) void*)(Ys + c*512), 16, 0, 0);
    }
  }
  __syncthreads();

  f32x4 acc[4][4];
  #pragma unroll
  for (int m=0;m<4;m++)
    #pragma unroll
    for (int n=0;n<4;n++)
      acc[m][n] = (f32x4){0.f,0.f,0.f,0.f};

  const int swz = (lrow & 7) << 4;
  #pragma unroll
  for (int ks = 0; ks < 4; ++ks){
    short8 av[4], bv[4];
    const int kb = (ks*64 + kgrp*16) ^ swz;
    #pragma unroll
    for (int m=0;m<4;m++){
      const int ra = wr*64 + m*16 + lrow;
      const int rb = wc*64 + m*16 + lrow;
      av[m] = *(const short8*)((const char*)Xs + ra*256 + kb);
      bv[m] = *(const short8*)((const char*)Ys + rb*256 + kb);
    }
    #pragma unroll
    for (int m=0;m<4;m++)
      #pragma unroll
      for (int n=0;n<4;n++)
        acc[m][n] = __builtin_amdgcn_mfma_f32_16x16x32_bf16(av[m], bv[n], acc[m][n], 0, 0, 0);
  }

  // diagonal: acc=0 -> key=fract(0)=0 = minimal (reference adds BIG)
  if (blockIdx.x == blockIdx.y && wr == wc && kgrp == (lrow >> 2)){
    #pragma unroll
    for (int r=0;r<4;r++)
      if ((lrow & 3) == r){
        #pragma unroll
        for (int m=0;m<4;m++) acc[m][m][r] = 0.0f;
      }
  }

  // packing + max-trees
  const int colb_loc = wc*64 + lrow;
  u32 orvr[4];
  #pragma unroll
  for (int n=0;n<4;n++) orvr[n] = (u32)(127 - colb_loc - n*16);
  const u32 kgco = (u32)(63 - kgrp*4);

  u32 pkc[4] = {0u,0u,0u,0u};
  u32 rpk[16];
  #pragma unroll
  for (int m=0;m<4;m++){
    #pragma unroll
    for (int r=0;r<4;r++){
      u32 kb[4];
      #pragma unroll
      for (int n=0;n<4;n++){
        const float a = acc[m][n][r];
        kb[n] = __float_as_uint(a - floorf(a));    // fract
      }
      const u32 b0 = (kb[0] & 0xFFFFFF80u) | orvr[0];
      const u32 b1 = (kb[1] & 0xFFFFFF80u) | orvr[1];
      const u32 b2 = (kb[2] & 0xFFFFFF80u) | orvr[2];
      const u32 b3 = (kb[3] & 0xFFFFFF80u) | orvr[3];
      const u32 x01 = b0 > b1 ? b0 : b1;
      const u32 x23 = b2 > b3 ? b2 : b3;
      rpk[m*4+r] = x01 > x23 ? x01 : x23;
      const u32 orvc = kgco - (u32)(m*16 + r);
      #pragma unroll
      for (int n=0;n<4;n++){
        const u32 c = (kb[n] & 0xFFFFFFC0u) | orvc;
        pkc[n] = c > pkc[n] ? c : pkc[n];
      }
    }
  }

  // col: combine across kgrp lanes (row id embedded, so shuffle-max keeps winner)
  #pragma unroll
  for (int n=0;n<4;n++){
    u32 o = (u32)__shfl_xor((int)pkc[n], 16, 64); pkc[n] = o > pkc[n] ? o : pkc[n];
    o = (u32)__shfl_xor((int)pkc[n], 32, 64);     pkc[n] = o > pkc[n] ? o : pkc[n];
  }

  __syncthreads();                                  // tiles consumed; reuse LDS
  u32* rowbuf = (u32*)Xs;   // [128][36] u32, pad-36 stride (2-way banks = free)
  u32* colred = (u32*)Ys;   // [2][128]
  {
    const int slot = wc*16 + lrow;
    #pragma unroll
    for (int m=0;m<4;m++)
      #pragma unroll
      for (int r=0;r<4;r++){
        const int row = wr*64 + m*16 + kgrp*4 + r;
        rowbuf[row*36 + slot] = rpk[m*4+r];
      }
    if (kgrp == 0){
      #pragma unroll
      for (int n=0;n<4;n++)
        colred[wr*128 + wc*64 + n*16 + lrow] = pkc[n];
    }
  }
  __syncthreads();

  if (tid < 128){
    const u32* base = rowbuf + tid*36;
    u32 best = 0u;
    #pragma unroll
    for (int q=0;q<8;q++){
      const uint4 t = *(const uint4*)(base + q*4);
      const u32 m1 = t.x > t.y ? t.x : t.y;
      const u32 m2 = t.z > t.w ? t.z : t.w;
      const u32 m3 = m1 > m2 ? m1 : m2;
      best = m3 > best ? m3 : best;
    }
    const int colg = 127 - (int)(best & 127u);
    rowpart[((size_t)pair*64 + blockIdx.x)*CNT + (brow + tid)] =
        ((u64)(~(best & 0xFFFFFF80u)) << 32) | (u32)(bcol + colg);
  } else {
    const int c = tid - 128;
    const u32 a0 = colred[c], a1 = colred[128 + c];
    const u32 w = a1 > a0 ? a1 : a0;
    const int rloc = (a1 > a0 ? 64 : 0) + (63 - (int)(w & 63u));
    colpart[((size_t)pair*64 + blockIdx.y)*CNT + (bcol + c)] =
        ((u64)(~(w & 0xFFFFFFC0u)) << 32) | (u32)(brow + rloc);
  }
}

// fused: reduce 64 row/col partials + select hard negative + exact dot
__global__ __launch_bounds__(256) void kpick(const float* __restrict__ xn,
    const u64* __restrict__ rowpart, const u64* __restrict__ colpart, float* __restrict__ neg){
  const int e = blockIdx.x*4 + (threadIdx.x>>6);   // 0..24575
  const int lane = threadIdx.x & 63;
  const int p = e >> 13, i = e & (CNT-1);
  const int xo[3] = {0, 2*CNT, 4*CNT};
  const int yo[3] = {CNT, 5*CNT, 3*CNT};
  u64 rv = rowpart[((size_t)p*64 + lane)*CNT + i];
  u64 cv = colpart[((size_t)p*64 + lane)*CNT + i];
  #pragma unroll
  for (int m=1;m<64;m<<=1){
    u64 o = __shfl_xor(rv, m, 64); rv = o < rv ? o : rv;
    o = __shfl_xor(cv, m, 64);     cv = o < cv ? o : cv;
  }
  const u32 rkey = (u32)(rv >> 32), ckey = (u32)(cv >> 32);
  int orow;
  if (rkey < ckey) orow = yo[p] + (int)(rv & 0xFFFFFFFFull);   // row branch -> Y row
  else             orow = xo[p] + (int)(cv & 0xFFFFFFFFull);   // col branch -> X row
  float d = wave_dot(xn + (size_t)(xo[p]+i)*DIM, xn + (size_t)orow*DIM, lane);
  if (lane == 0) neg[p*CNT + i] = d;
}

// u,v + 5 moment partials (constant-centered) in one pass
__global__ __launch_bounds__(256) void kuv(const float* __restrict__ pos, const float* __restrict__ neg,
    float* __restrict__ u, float* __restrict__ v, float* __restrict__ mpart){
  __shared__ float red[4];
  const int tid = threadIdx.x;
  const int idx = blockIdx.x*256 + tid;
  const float d = (idx < 3*CNT) ? pos[idx] : neg[idx - 3*CNT];
  const float om = 1.0f - d;
  const float sq = sqrtf(2.0f*om + 1e-12f);
  const float uu = om - sq;
  u[idx] = uu;
  v[idx] = sq;
  const float cu = uu + 0.35f;
  const float cv = sq - 0.80f;
  const float s0 = block_sum(uu, red, tid);
  const float s1 = block_sum(sq, red, tid);
  const float s2 = block_sum(cu*cu, red, tid);
  const float s3 = block_sum(cu*cv, red, tid);
  const float s4 = block_sum(cv*cv, red, tid);
  if (tid == 0){
    float* mp = mpart + blockIdx.x*5;
    mp[0]=s0; mp[1]=s1; mp[2]=s2; mp[3]=s3; mp[4]=s4;
  }
}

// combine moment partials; per-alpha mean & inv_std
__global__ __launch_bounds__(256) void kmom(const float* __restrict__ mpart,
    float* __restrict__ amean, float* __restrict__ aistd){
  __shared__ float red[4];
  __shared__ float sm[5];
  const int tid = threadIdx.x;
  float a0=0.f,a1=0.f,a2=0.f,a3=0.f,a4=0.f;
  if (tid < 192){
    const float* mp = mpart + tid*5;
    a0=mp[0]; a1=mp[1]; a2=mp[2]; a3=mp[3]; a4=mp[4];
  }
  a0 = block_sum(a0, red, tid);
  a1 = block_sum(a1, red, tid);
  a2 = block_sum(a2, red, tid);
  a3 = block_sum(a3, red, tid);
  a4 = block_sum(a4, red, tid);
  if (tid == 0){ sm[0]=a0; sm[1]=a1; sm[2]=a2; sm[3]=a3; sm[4]=a4; }
  __syncthreads();
  const float N = 49152.0f;
  const float mu_u = sm[0]/N, mu_v = sm[1]/N;
  const float du = mu_u + 0.35f, dv = mu_v - 0.80f;
  const float Suu = sm[2] - N*du*du;
  const float Suv = sm[3] - N*du*dv;
  const float Svv = sm[4] - N*dv*dv;
  if (tid < 200){
    const float a = -1.0f + 0.01f*(float)tid;
    amean[tid] = a*mu_u + mu_v;
    const float var = (a*a*Suu + 2.0f*a*Suv + Svv) / 49151.0f;
    aistd[tid] = 1.0f/sqrtf(var);
  }
}

// kbce: grid (200 alphas x 8 chunks); partial softplus sums
__global__ __launch_bounds__(256) void kbce(const float* __restrict__ u, const float* __restrict__ v,
    const float* __restrict__ amean, const float* __restrict__ aistd, float* __restrict__ psum){
  __shared__ float red[4];
  const int tid = threadIdx.x;
  const int a = blockIdx.x >> 3, c = blockIdx.x & 7;
  const float av = -1.0f + 0.01f*(float)a;
  const float mean = amean[a], istd = aistd[a];
  const int base = c*6144;
  float s = 0.0f;
  #pragma unroll 4
  for (int k = 0; k < 24; ++k){
    const int idx = base + k*256 + tid;
    const float z = (fmaf(av, u[idx], v[idx]) - mean) * istd;
    const float zz = (idx < 3*CNT) ? z : -z;
    s += fmaxf(zz, 0.0f) + log1pf(expf(-fabsf(zz)));
  }
  s = block_sum(s, red, tid);
  if (tid == 0) psum[blockIdx.x] = s;
}

// argmin(bce) -> alpha; losses, mask ratio, l_mean; 8 outputs
__global__ __launch_bounds__(256) void kfinal(const float* __restrict__ pos, const float* __restrict__ neg,
    const float* __restrict__ psum, const float* __restrict__ l_a_adv, const float* __restrict__ l_p_adv,
    float* __restrict__ out){
  __shared__ float sbce[200];
  __shared__ float sal[2];
  __shared__ float red[4];
  const int tid = threadIdx.x;
  if (tid < 200){
    float s = 0.f;
    #pragma unroll
    for (int c=0;c<8;c++) s += psum[tid*8 + c];
    sbce[tid] = s;
  }
  __syncthreads();
  if (tid == 0){
    float best = sbce[0]; int bk = 0;
    for (int k=1;k<200;k++){
      const float vv = sbce[k];
      if (vv < best){ best = vv; bk = k; }
    }
    const float aopt = -1.0f + 0.01f*(float)bk;
    sal[0] = aopt;
    sal[1] = aopt * 0.005f;
  }
  __syncthreads();
  const float alpha = sal[1];

  float sc=0.f, sar=0.f, saa=0.f, sm=0.f, sla=0.f, slp=0.f;
  for (int i = tid; i < CNT; i += 256){
    const float pap = pos[i],        nap = neg[i];
    const float par = pos[CNT+i],    nar = neg[CNT+i];
    const float paa = pos[2*CNT+i],  naa = neg[2*CNT+i];
    const float cp = fminf(fmaxf(pap, -1.0f), 1.0f);
    const float cn = fminf(fmaxf(nap, -1.0f), 1.0f);
    const float m = (0.36f + acosf(cp) - acosf(cn) > 0.0f) ? 1.0f : 0.0f;
    #define DDIST(d) (alpha*(1.0f-(d)) + (1.0f-alpha)*sqrtf(2.0f*(1.0f-(d)) + 1e-12f))
    sc  += (DDIST(pap) - DDIST(nap)) * m;
    sar += (l_p_adv[i]*DDIST(par) - DDIST(nar)) * m;
    saa += (l_a_adv[i]*DDIST(paa) - DDIST(naa)) * m;
    sm  += m;
    sla += l_a_adv[i];
    slp += l_p_adv[i];
  }
  float vals[6] = {sc, sar, saa, sm, sla, slp};
  float tot[6];
  for (int vv=0; vv<6; vv++){
    tot[vv] = block_sum(vals[vv], red, tid);
  }
  if (tid == 0){
    const float lc  = tot[0] / (float)CNT;
    const float lar = tot[1] / (float)CNT;
    const float laa = tot[2] / (float)CNT;
    out[0] = (lc + lar + laa) / 3.0f;
    out[1] = lc;
    out[2] = lar;
    out[3] = laa;
    out[4] = (tot[4]/(float)CNT + tot[5]/(float)CNT) * 0.5f;
    out[5] = sal[1];
    out[6] = sal[0];
    out[7] = tot[3] / (float)CNT;
  }
}

extern "C" void kernel_launch(void* const* d_in, const int* in_sizes, int n_in,
                              void* d_out, int out_size, void* d_ws, size_t ws_size,
                              hipStream_t stream) {
  const float* descs = (const float*)d_in[0];
  const float* l_a   = (const float*)d_in[1];
  const float* l_p   = (const float*)d_in[2];
  float* out = (float*)d_out;
  char* ws = (char*)d_ws;

  float* xn  = (float*)(ws + OFF_XN);
  float* pos = (float*)(ws + OFF_POS);
  float* neg = (float*)(ws + OFF_NEG);
  u64* rowpart = (u64*)(ws + OFF_ROWPART);
  u64* colpart = (u64*)(ws + OFF_COLPART);
  float* u     = (float*)(ws + OFF_U);
  float* v     = (float*)(ws + OFF_V);
  float* mpart = (float*)(ws + OFF_MPART);
  float* amean = (float*)(ws + OFF_AMEAN);
  float* aistd = (float*)(ws + OFF_AISTD);
  float* psum  = (float*)(ws + OFF_PSUM);
  unsigned int* xnb32 = (unsigned int*)(ws + OFF_XNB);
  const unsigned short* xnb = (const unsigned short*)(ws + OFF_XNB);

  knorm  <<<(6*CNT)/4, 256, 0, stream>>>(descs, xn, xnb32);
  kdiag  <<<(3*CNT)/4, 256, 0, stream>>>(xn, pos);
  kgemm  <<<dim3(64,64,3), 256, 0, stream>>>(xnb, rowpart, colpart);
  kpick  <<<(3*CNT)/4, 256, 0, stream>>>(xn, rowpart, colpart, neg);
  kuv    <<<192, 256, 0, stream>>>(pos, neg, u, v, mpart);
  kmom   <<<1, 256, 0, stream>>>(mpart, amean, aistd);
  kbce   <<<1600, 256, 0, stream>>>(u, v, amean, aistd, psum);
  kfinal <<<1, 256, 0, stream>>>(pos, neg, psum, l_a, l_p, out);
}

// Round 5
// 195.897 us; speedup vs baseline: 7.2790x; 1.1118x over previous
//
#include <hip/hip_runtime.h>
#include <stdint.h>

#define CNT 8192
#define DIM 128

typedef unsigned long long u64;
typedef unsigned int u32;

// ---- workspace layout (bytes) ----
#define OFF_XN      ((size_t)0)                            // 6*CNT*DIM*4
#define OFF_POS     ((size_t)6*CNT*DIM*4)                  // 3*CNT floats
#define OFF_NEG     (OFF_POS + (size_t)3*CNT*4)            // 3*CNT floats
#define OFF_ROWPART (OFF_NEG + (size_t)3*CNT*4)            // 3*64*CNT u64
#define OFF_COLPART (OFF_ROWPART + (size_t)3*64*CNT*8)     // 3*64*CNT u64
#define OFF_U       (OFF_COLPART + (size_t)3*64*CNT*8)     // 6*CNT floats
#define OFF_V       (OFF_U + (size_t)6*CNT*4)              // 6*CNT floats
#define OFF_MPART   (OFF_V + (size_t)6*CNT*4)              // 192*5 floats
#define OFF_AMEAN   (OFF_MPART + (size_t)4096)             // 200 floats
#define OFF_AISTD   (OFF_AMEAN + (size_t)1024)             // 200 floats
#define OFF_PSUM    (OFF_AISTD + (size_t)1024)             // 1600 floats
#define OFF_XNB     (OFF_PSUM + (size_t)8192)              // 6*CNT*DIM bf16

typedef __attribute__((ext_vector_type(8))) short short8;
typedef __attribute__((ext_vector_type(4))) float f32x4;

__device__ __forceinline__ float block_sum(float x, float* red, int tid){
  #pragma unroll
  for (int m=1;m<64;m<<=1) x += __shfl_xor(x, m, 64);
  if ((tid & 63) == 0) red[tid>>6] = x;
  __syncthreads();
  const float r = red[0]+red[1]+red[2]+red[3];
  __syncthreads();
  return r;
}

// row-normalize: f32 xn; bf16 xnb with A-side (even segments) pre-scaled by 0.25
__global__ __launch_bounds__(256) void knorm(const float* __restrict__ in, float* __restrict__ xn,
                                             unsigned int* __restrict__ xnb32){
  const int row  = blockIdx.x*4 + (threadIdx.x>>6);
  const int lane = threadIdx.x & 63;
  const float2 v = *(const float2*)(in + (size_t)row*DIM + lane*2);
  float ss = v.x*v.x + v.y*v.y;
  #pragma unroll
  for (int m=1;m<64;m<<=1) ss += __shfl_xor(ss, m, 64);
  const float n = sqrtf(ss);
  float2 o; o.x = v.x/n; o.y = v.y/n;
  *(float2*)(xn + (size_t)row*DIM + lane*2) = o;
  const float sc = (row & CNT) ? 1.0f : 0.25f;   // segments 0,2,4 (A-side) scaled
  unsigned int ux = __float_as_uint(o.x*sc), uy = __float_as_uint(o.y*sc);
  ux = (ux + 0x7FFFu + ((ux>>16)&1u)) >> 16;
  uy = (uy + 0x7FFFu + ((uy>>16)&1u)) >> 16;
  xnb32[(size_t)row*64 + lane] = ux | (uy<<16);
}

// ---------------- MFMA bf16 GEMM, BK=32 double-buffered + fract-key argmin epilogue ----------------
// acc = dot/4 (A pre-scaled). key = fract(acc): max key == min dm (dm = 1/dot + eps).
// Row pack: [key:25][~col7:7]; Col pack: [key:26][~row6:6]. u32 max == argmax + lowest-index ties.
// LDS per chunk: [128 rows][32 k] bf16, 64B/row; phys 16B-slot = k_slot ^ ((row>>1)&3) -> conflict-free ds_read_b128.
__device__ __forceinline__ void stage_chunk(const unsigned short* __restrict__ G, int tilebase,
    int c, unsigned short* L, int wid, int lane){
  #pragma unroll
  for (int t=0;t<2;t++){
    const int j = wid*2 + t;                       // 1KB inst id (16 rows)
    const int row = j*16 + (lane>>2);
    const int slog = (lane&3) ^ ((lane>>3)&3);     // logical k-slot this phys slot holds
    const unsigned short* g = G + (size_t)(tilebase + row)*DIM + c*32 + slog*8;
    __builtin_amdgcn_global_load_lds((const __attribute__((address_space(1))) void*)g,
        (__attribute__((address_space(3))) void*)(L + j*512), 16, 0, 0);
  }
}

__global__ __launch_bounds__(256) void kgemm(const unsigned short* __restrict__ xnb,
    u64* __restrict__ rowpart, u64* __restrict__ colpart){
  __shared__ __align__(16) unsigned short S[4][128*32];   // 32 KB total: buf0{X,Y}, buf1{X,Y}
  const int pair = blockIdx.z;
  const int xo3[3] = {0, 2*CNT, 4*CNT};
  const int yo3[3] = {CNT, 5*CNT, 3*CNT};
  const unsigned short* __restrict__ X = xnb + (size_t)xo3[pair]*DIM;
  const unsigned short* __restrict__ Y = xnb + (size_t)yo3[pair]*DIM;
  const int brow = blockIdx.y*128, bcol = blockIdx.x*128;
  const int tid = threadIdx.x, lane = tid & 63, wid = tid >> 6;
  const int wr = wid >> 1, wc = wid & 1;           // 2x2 waves, 64x64 tiles
  const int lrow = lane & 15, kgrp = lane >> 4;

  f32x4 acc[4][4];
  #pragma unroll
  for (int m=0;m<4;m++)
    #pragma unroll
    for (int n=0;n<4;n++)
      acc[m][n] = (f32x4){0.f,0.f,0.f,0.f};

  stage_chunk(X, brow, 0, S[0], wid, lane);
  stage_chunk(Y, bcol, 0, S[1], wid, lane);
  __syncthreads();

  const int swzb = ((lrow>>1)&3) << 4;
  #pragma unroll
  for (int c=0;c<4;c++){
    if (c<3){
      stage_chunk(X, brow, c+1, S[((c+1)&1)*2],     wid, lane);
      stage_chunk(Y, bcol, c+1, S[((c+1)&1)*2 + 1], wid, lane);
    }
    const char* LX = (const char*)S[(c&1)*2];
    const char* LY = (const char*)S[(c&1)*2 + 1];
    const int kb = (kgrp*16) ^ swzb;
    short8 av[4], bv[4];
    #pragma unroll
    for (int m=0;m<4;m++){
      av[m] = *(const short8*)(LX + (wr*64 + m*16 + lrow)*64 + kb);
      bv[m] = *(const short8*)(LY + (wc*64 + m*16 + lrow)*64 + kb);
    }
    #pragma unroll
    for (int m=0;m<4;m++)
      #pragma unroll
      for (int n=0;n<4;n++)
        acc[m][n] = __builtin_amdgcn_mfma_f32_16x16x32_bf16(av[m], bv[n], acc[m][n], 0, 0, 0);
    if (c<3) __syncthreads();
  }

  // diagonal: acc=0 -> key=fract(0)=0 = minimal (reference adds BIG)
  if (blockIdx.x == blockIdx.y && wr == wc && kgrp == (lrow >> 2)){
    #pragma unroll
    for (int r=0;r<4;r++)
      if ((lrow & 3) == r){
        #pragma unroll
        for (int m=0;m<4;m++) acc[m][m][r] = 0.0f;
      }
  }

  // packing + max-trees
  const int colb_loc = wc*64 + lrow;
  u32 orvr[4];
  #pragma unroll
  for (int n=0;n<4;n++) orvr[n] = (u32)(127 - colb_loc - n*16);
  const u32 kgco = (u32)(63 - kgrp*4);

  u32 pkc[4] = {0u,0u,0u,0u};
  u32 rpk[16];
  #pragma unroll
  for (int m=0;m<4;m++){
    #pragma unroll
    for (int r=0;r<4;r++){
      u32 kb2[4];
      #pragma unroll
      for (int n=0;n<4;n++){
        const float a = acc[m][n][r];
        kb2[n] = __float_as_uint(a - floorf(a));    // fract
      }
      const u32 b0 = (kb2[0] & 0xFFFFFF80u) | orvr[0];
      const u32 b1 = (kb2[1] & 0xFFFFFF80u) | orvr[1];
      const u32 b2 = (kb2[2] & 0xFFFFFF80u) | orvr[2];
      const u32 b3 = (kb2[3] & 0xFFFFFF80u) | orvr[3];
      const u32 x01 = b0 > b1 ? b0 : b1;
      const u32 x23 = b2 > b3 ? b2 : b3;
      rpk[m*4+r] = x01 > x23 ? x01 : x23;
      const u32 orvc = kgco - (u32)(m*16 + r);
      #pragma unroll
      for (int n=0;n<4;n++){
        const u32 c = (kb2[n] & 0xFFFFFFC0u) | orvc;
        pkc[n] = c > pkc[n] ? c : pkc[n];
      }
    }
  }

  // col: combine across kgrp lanes (row id embedded, so shuffle-max keeps winner)
  #pragma unroll
  for (int n=0;n<4;n++){
    u32 o = (u32)__shfl_xor((int)pkc[n], 16, 64); pkc[n] = o > pkc[n] ? o : pkc[n];
    o = (u32)__shfl_xor((int)pkc[n], 32, 64);     pkc[n] = o > pkc[n] ? o : pkc[n];
  }

  __syncthreads();                                  // tiles consumed; reuse LDS
  u32* rowbuf = (u32*)S;                            // [128][36] u32 = 18KB
  u32* colred = (u32*)((char*)S + 20480);           // [2][128] u32 = 1KB
  {
    const int slot = wc*16 + lrow;
    #pragma unroll
    for (int m=0;m<4;m++)
      #pragma unroll
      for (int r=0;r<4;r++){
        const int row = wr*64 + m*16 + kgrp*4 + r;
        rowbuf[row*36 + slot] = rpk[m*4+r];
      }
    if (kgrp == 0){
      #pragma unroll
      for (int n=0;n<4;n++)
        colred[wr*128 + wc*64 + n*16 + lrow] = pkc[n];
    }
  }
  __syncthreads();

  if (tid < 128){
    const u32* base = rowbuf + tid*36;
    u32 best = 0u;
    #pragma unroll
    for (int q=0;q<8;q++){
      const uint4 t = *(const uint4*)(base + q*4);
      const u32 m1 = t.x > t.y ? t.x : t.y;
      const u32 m2 = t.z > t.w ? t.z : t.w;
      const u32 m3 = m1 > m2 ? m1 : m2;
      best = m3 > best ? m3 : best;
    }
    const int colg = 127 - (int)(best & 127u);
    rowpart[((size_t)pair*64 + blockIdx.x)*CNT + (brow + tid)] =
        ((u64)(~(best & 0xFFFFFF80u)) << 32) | (u32)(bcol + colg);
  } else {
    const int c = tid - 128;
    const u32 a0 = colred[c], a1 = colred[128 + c];
    const u32 w = a1 > a0 ? a1 : a0;
    const int rloc = (a1 > a0 ? 64 : 0) + (63 - (int)(w & 63u));
    colpart[((size_t)pair*64 + blockIdx.y)*CNT + (bcol + c)] =
        ((u64)(~(w & 0xFFFFFFC0u)) << 32) | (u32)(brow + rloc);
  }
}

// fused: reduce 64 row/col partials + select hard negative + exact dots (pos & neg)
__global__ __launch_bounds__(256) void kpick(const float* __restrict__ xn,
    const u64* __restrict__ rowpart, const u64* __restrict__ colpart,
    float* __restrict__ pos, float* __restrict__ neg){
  const int e = blockIdx.x*4 + (threadIdx.x>>6);   // 0..24575
  const int lane = threadIdx.x & 63;
  const int p = e >> 13, i = e & (CNT-1);
  const int xo[3] = {0, 2*CNT, 4*CNT};
  const int yo[3] = {CNT, 5*CNT, 3*CNT};
  u64 rv = rowpart[((size_t)p*64 + lane)*CNT + i];
  u64 cv = colpart[((size_t)p*64 + lane)*CNT + i];
  #pragma unroll
  for (int m=1;m<64;m<<=1){
    u64 o = __shfl_xor(rv, m, 64); rv = o < rv ? o : rv;
    o = __shfl_xor(cv, m, 64);     cv = o < cv ? o : cv;
  }
  const u32 rkey = (u32)(rv >> 32), ckey = (u32)(cv >> 32);
  int orow;
  if (rkey < ckey) orow = yo[p] + (int)(rv & 0xFFFFFFFFull);   // row branch -> Y row
  else             orow = xo[p] + (int)(cv & 0xFFFFFFFFull);   // col branch -> X row
  const float2 va = *(const float2*)(xn + (size_t)(xo[p]+i)*DIM + lane*2);
  const float2 vp = *(const float2*)(xn + (size_t)(yo[p]+i)*DIM + lane*2);
  const float2 vn = *(const float2*)(xn + (size_t)orow*DIM + lane*2);
  float dp = va.x*vp.x + va.y*vp.y;
  float dn = va.x*vn.x + va.y*vn.y;
  #pragma unroll
  for (int m=1;m<64;m<<=1){
    dp += __shfl_xor(dp, m, 64);
    dn += __shfl_xor(dn, m, 64);
  }
  if (lane == 0){ pos[p*CNT + i] = dp; neg[p*CNT + i] = dn; }
}

// u,v + 5 moment partials (constant-centered) in one pass
__global__ __launch_bounds__(256) void kuv(const float* __restrict__ pos, const float* __restrict__ neg,
    float* __restrict__ u, float* __restrict__ v, float* __restrict__ mpart){
  __shared__ float red[4];
  const int tid = threadIdx.x;
  const int idx = blockIdx.x*256 + tid;
  const float d = (idx < 3*CNT) ? pos[idx] : neg[idx - 3*CNT];
  const float om = 1.0f - d;
  const float sq = sqrtf(2.0f*om + 1e-12f);
  const float uu = om - sq;
  u[idx] = uu;
  v[idx] = sq;
  const float cu = uu + 0.35f;
  const float cv = sq - 0.80f;
  const float s0 = block_sum(uu, red, tid);
  const float s1 = block_sum(sq, red, tid);
  const float s2 = block_sum(cu*cu, red, tid);
  const float s3 = block_sum(cu*cv, red, tid);
  const float s4 = block_sum(cv*cv, red, tid);
  if (tid == 0){
    float* mp = mpart + blockIdx.x*5;
    mp[0]=s0; mp[1]=s1; mp[2]=s2; mp[3]=s3; mp[4]=s4;
  }
}

// combine moment partials; per-alpha mean & inv_std
__global__ __launch_bounds__(256) void kmom(const float* __restrict__ mpart,
    float* __restrict__ amean, float* __restrict__ aistd){
  __shared__ float red[4];
  __shared__ float sm[5];
  const int tid = threadIdx.x;
  float a0=0.f,a1=0.f,a2=0.f,a3=0.f,a4=0.f;
  if (tid < 192){
    const float* mp = mpart + tid*5;
    a0=mp[0]; a1=mp[1]; a2=mp[2]; a3=mp[3]; a4=mp[4];
  }
  a0 = block_sum(a0, red, tid);
  a1 = block_sum(a1, red, tid);
  a2 = block_sum(a2, red, tid);
  a3 = block_sum(a3, red, tid);
  a4 = block_sum(a4, red, tid);
  if (tid == 0){ sm[0]=a0; sm[1]=a1; sm[2]=a2; sm[3]=a3; sm[4]=a4; }
  __syncthreads();
  const float N = 49152.0f;
  const float mu_u = sm[0]/N, mu_v = sm[1]/N;
  const float du = mu_u + 0.35f, dv = mu_v - 0.80f;
  const float Suu = sm[2] - N*du*du;
  const float Suv = sm[3] - N*du*dv;
  const float Svv = sm[4] - N*dv*dv;
  if (tid < 200){
    const float a = -1.0f + 0.01f*(float)tid;
    amean[tid] = a*mu_u + mu_v;
    const float var = (a*a*Suu + 2.0f*a*Suv + Svv) / 49151.0f;
    aistd[tid] = 1.0f/sqrtf(var);
  }
}

// kbce: grid (200 alphas x 8 chunks); partial softplus sums
__global__ __launch_bounds__(256) void kbce(const float* __restrict__ u, const float* __restrict__ v,
    const float* __restrict__ amean, const float* __restrict__ aistd, float* __restrict__ psum){
  __shared__ float red[4];
  const int tid = threadIdx.x;
  const int a = blockIdx.x >> 3, c = blockIdx.x & 7;
  const float av = -1.0f + 0.01f*(float)a;
  const float mean = amean[a], istd = aistd[a];
  const int base = c*6144;
  float s = 0.0f;
  #pragma unroll 4
  for (int k = 0; k < 24; ++k){
    const int idx = base + k*256 + tid;
    const float z = (fmaf(av, u[idx], v[idx]) - mean) * istd;
    const float zz = (idx < 3*CNT) ? z : -z;
    s += fmaxf(zz, 0.0f) + log1pf(expf(-fabsf(zz)));
  }
  s = block_sum(s, red, tid);
  if (tid == 0) psum[blockIdx.x] = s;
}

// argmin(bce) -> alpha; losses, mask ratio, l_mean; 8 outputs
__global__ __launch_bounds__(256) void kfinal(const float* __restrict__ pos, const float* __restrict__ neg,
    const float* __restrict__ psum, const float* __restrict__ l_a_adv, const float* __restrict__ l_p_adv,
    float* __restrict__ out){
  __shared__ float sbce[200];
  __shared__ float sal[2];
  __shared__ float red[4];
  const int tid = threadIdx.x;
  if (tid < 200){
    float s = 0.f;
    #pragma unroll
    for (int c=0;c<8;c++) s += psum[tid*8 + c];
    sbce[tid] = s;
  }
  __syncthreads();
  if (tid == 0){
    float best = sbce[0]; int bk = 0;
    for (int k=1;k<200;k++){
      const float vv = sbce[k];
      if (vv < best){ best = vv; bk = k; }
    }
    const float aopt = -1.0f + 0.01f*(float)bk;
    sal[0] = aopt;
    sal[1] = aopt * 0.005f;
  }
  __syncthreads();
  const float alpha = sal[1];

  float sc=0.f, sar=0.f, saa=0.f, sm=0.f, sla=0.f, slp=0.f;
  for (int i = tid; i < CNT; i += 256){
    const float pap = pos[i],        nap = neg[i];
    const float par = pos[CNT+i],    nar = neg[CNT+i];
    const float paa = pos[2*CNT+i],  naa = neg[2*CNT+i];
    const float cp = fminf(fmaxf(pap, -1.0f), 1.0f);
    const float cn = fminf(fmaxf(nap, -1.0f), 1.0f);
    const float m = (0.36f + acosf(cp) - acosf(cn) > 0.0f) ? 1.0f : 0.0f;
    #define DDIST(d) (alpha*(1.0f-(d)) + (1.0f-alpha)*sqrtf(2.0f*(1.0f-(d)) + 1e-12f))
    sc  += (DDIST(pap) - DDIST(nap)) * m;
    sar += (l_p_adv[i]*DDIST(par) - DDIST(nar)) * m;
    saa += (l_a_adv[i]*DDIST(paa) - DDIST(naa)) * m;
    sm  += m;
    sla += l_a_adv[i];
    slp += l_p_adv[i];
  }
  float vals[6] = {sc, sar, saa, sm, sla, slp};
  float tot[6];
  for (int vv=0; vv<6; vv++){
    tot[vv] = block_sum(vals[vv], red, tid);
  }
  if (tid == 0){
    const float lc  = tot[0] / (float)CNT;
    const float lar = tot[1] / (float)CNT;
    const float laa = tot[2] / (float)CNT;
    out[0] = (lc + lar + laa) / 3.0f;
    out[1] = lc;
    out[2] = lar;
    out[3] = laa;
    out[4] = (tot[4]/(float)CNT + tot[5]/(float)CNT) * 0.5f;
    out[5] = sal[1];
    out[6] = sal[0];
    out[7] = tot[3] / (float)CNT;
  }
}

extern "C" void kernel_launch(void* const* d_in, const int* in_sizes, int n_in,
                              void* d_out, int out_size, void* d_ws, size_t ws_size,
                              hipStream_t stream) {
  const float* descs = (const float*)d_in[0];
  const float* l_a   = (const float*)d_in[1];
  const float* l_p   = (const float*)d_in[2];
  float* out = (float*)d_out;
  char* ws = (char*)d_ws;

  float* xn  = (float*)(ws + OFF_XN);
  float* pos = (float*)(ws + OFF_POS);
  float* neg = (float*)(ws + OFF_NEG);
  u64* rowpart = (u64*)(ws + OFF_ROWPART);
  u64* colpart = (u64*)(ws + OFF_COLPART);
  float* u     = (float*)(ws + OFF_U);
  float* v     = (float*)(ws + OFF_V);
  float* mpart = (float*)(ws + OFF_MPART);
  float* amean = (float*)(ws + OFF_AMEAN);
  float* aistd = (float*)(ws + OFF_AISTD);
  float* psum  = (float*)(ws + OFF_PSUM);
  unsigned int* xnb32 = (unsigned int*)(ws + OFF_XNB);
  const unsigned short* xnb = (const unsigned short*)(ws + OFF_XNB);

  knorm  <<<(6*CNT)/4, 256, 0, stream>>>(descs, xn, xnb32);
  kgemm  <<<dim3(64,64,3), 256, 0, stream>>>(xnb, rowpart, colpart);
  kpick  <<<(3*CNT)/4, 256, 0, stream>>>(xn, rowpart, colpart, pos, neg);
  kuv    <<<192, 256, 0, stream>>>(pos, neg, u, v, mpart);
  kmom   <<<1, 256, 0, stream>>>(mpart, amean, aistd);
  kbce   <<<1600, 256, 0, stream>>>(u, v, amean, aistd, psum);
  kfinal <<<1, 256, 0, stream>>>(pos, neg, psum, l_a, l_p, out);
}

// Round 7
// 156.638 us; speedup vs baseline: 9.1034x; 1.2506x over previous
//
#include <hip/hip_runtime.h>
#include <stdint.h>

#define CNT 8192
#define DIM 128

typedef unsigned long long u64;
typedef unsigned int u32;

// ---- workspace layout (bytes) ----
#define OFF_POS     ((size_t)0)                            // 3*CNT f32
#define OFF_NEG     (OFF_POS + (size_t)3*CNT*4)            // 3*CNT f32
#define OFF_ROWPART (OFF_NEG + (size_t)3*CNT*4)            // 3*64*CNT u32
#define OFF_COLPART (OFF_ROWPART + (size_t)3*64*CNT*4)     // 3*64*CNT u32
#define OFF_U       (OFF_COLPART + (size_t)3*64*CNT*4)     // 6*CNT f32
#define OFF_V       (OFF_U + (size_t)6*CNT*4)              // 6*CNT f32
#define OFF_MPART   (OFF_V + (size_t)6*CNT*4)              // 6144*5 f32
#define OFF_AMEAN   (OFF_MPART + (size_t)6144*5*4)         // 200 f32
#define OFF_AISTD   (OFF_AMEAN + (size_t)1024)             // 200 f32
#define OFF_PSUM    (OFF_AISTD + (size_t)1024)             // 1600 f32
#define OFF_XNB     (OFF_PSUM + (size_t)8192)              // 6*CNT*DIM bf16
// total ~26 MiB

typedef __attribute__((ext_vector_type(8))) short short8;
typedef __attribute__((ext_vector_type(4))) float f32x4;

__device__ __forceinline__ float fract1(float x){
#if __has_builtin(__builtin_amdgcn_fractf)
  return __builtin_amdgcn_fractf(x);
#else
  return x - floorf(x);
#endif
}
__device__ __forceinline__ u32 umax2(u32 a, u32 b){ return a > b ? a : b; }
__device__ __forceinline__ u32 umax3(u32 a, u32 b, u32 c){ u32 t = a > b ? a : b; return t > c ? t : c; }

__device__ __forceinline__ float block_sum(float x, float* red, int tid){
  #pragma unroll
  for (int m=1;m<64;m<<=1) x += __shfl_xor(x, m, 64);
  if ((tid & 63) == 0) red[tid>>6] = x;
  __syncthreads();
  const float r = red[0]+red[1]+red[2]+red[3];
  __syncthreads();
  return r;
}

// row-normalize -> bf16 only; A-side (segments 0,2,4) pre-scaled by 0.25
__global__ __launch_bounds__(256) void knorm(const float* __restrict__ in,
                                             unsigned int* __restrict__ xnb32){
  const int row  = blockIdx.x*4 + (threadIdx.x>>6);
  const int lane = threadIdx.x & 63;
  const float2 v = *(const float2*)(in + (size_t)row*DIM + lane*2);
  float ss = v.x*v.x + v.y*v.y;
  #pragma unroll
  for (int m=1;m<64;m<<=1) ss += __shfl_xor(ss, m, 64);
  const float sc = ((row & CNT) ? 1.0f : 0.25f) / sqrtf(ss);
  unsigned int ux = __float_as_uint(v.x*sc), uy = __float_as_uint(v.y*sc);
  ux = (ux + 0x7FFFu + ((ux>>16)&1u)) >> 16;
  uy = (uy + 0x7FFFu + ((uy>>16)&1u)) >> 16;
  xnb32[(size_t)row*64 + lane] = ux | (uy<<16);
}

// ---------------- MFMA bf16 GEMM, BK=32 dbuf + fract-key argmin epilogue ----------------
// acc = dot/4 (A pre-scaled). key = fract(acc): larger key == smaller dm (dm = 1/dot + eps).
// In-block packs: row [key25 | ~col7], col [key26 | ~row6] -> u32 max = argmax + lowest-idx ties.
// Global partials: u32 [inv_key19 | index13], min-reduced in kpick.
__global__ __launch_bounds__(256) void kgemm(const unsigned short* __restrict__ xnb,
    u32* __restrict__ rowpart, u32* __restrict__ colpart){
  __shared__ __align__(16) unsigned short S[4][128*32];   // 32 KB: buf0{X,Y}, buf1{X,Y}
  const int pair = blockIdx.z;
  const int xo3[3] = {0, 2*CNT, 4*CNT};
  const int yo3[3] = {CNT, 5*CNT, 3*CNT};
  const unsigned short* __restrict__ X = xnb + (size_t)xo3[pair]*DIM;
  const unsigned short* __restrict__ Y = xnb + (size_t)yo3[pair]*DIM;
  const int brow = blockIdx.y*128, bcol = blockIdx.x*128;
  const int tid = threadIdx.x, lane = tid & 63, wid = tid >> 6;
  const int wr = wid >> 1, wc = wid & 1;           // 2x2 waves, 64x64 tiles
  const int lrow = lane & 15, kgrp = lane >> 4;

  // per-lane staging sources (16B/lane/inst), hoisted once; chunk advance folded into pointer
  const int j0 = wid*2, j1 = wid*2 + 1;
  const int r0 = j0*16 + (lane>>2), r1 = j1*16 + (lane>>2);
  const int slog = (lane&3) ^ ((lane>>3)&3);       // logical k-slot this phys slot holds
  const unsigned short* gx0 = X + (size_t)(brow + r0)*DIM + slog*8;
  const unsigned short* gx1 = X + (size_t)(brow + r1)*DIM + slog*8;
  const unsigned short* gy0 = Y + (size_t)(bcol + r0)*DIM + slog*8;
  const unsigned short* gy1 = Y + (size_t)(bcol + r1)*DIM + slog*8;

#define STAGEC(c) do{ \
    unsigned short* LX = S[((c)&1)*2]; \
    unsigned short* LY = S[((c)&1)*2 + 1]; \
    __builtin_amdgcn_global_load_lds((const __attribute__((address_space(1))) void*)(gx0 + (c)*32), \
        (__attribute__((address_space(3))) void*)(LX + j0*512), 16, 0, 0); \
    __builtin_amdgcn_global_load_lds((const __attribute__((address_space(1))) void*)(gx1 + (c)*32), \
        (__attribute__((address_space(3))) void*)(LX + j1*512), 16, 0, 0); \
    __builtin_amdgcn_global_load_lds((const __attribute__((address_space(1))) void*)(gy0 + (c)*32), \
        (__attribute__((address_space(3))) void*)(LY + j0*512), 16, 0, 0); \
    __builtin_amdgcn_global_load_lds((const __attribute__((address_space(1))) void*)(gy1 + (c)*32), \
        (__attribute__((address_space(3))) void*)(LY + j1*512), 16, 0, 0); \
  }while(0)

  f32x4 acc[4][4];
  #pragma unroll
  for (int m=0;m<4;m++)
    #pragma unroll
    for (int n=0;n<4;n++)
      acc[m][n] = (f32x4){0.f,0.f,0.f,0.f};

  STAGEC(0);
  __syncthreads();

  const int swzb = ((lrow>>1)&3) << 4;
  #pragma unroll
  for (int c=0;c<4;c++){
    if (c<3) STAGEC(c+1);
    const char* LX = (const char*)S[(c&1)*2];
    const char* LY = (const char*)S[(c&1)*2 + 1];
    const int kb = (kgrp*16) ^ swzb;
    short8 av[4], bv[4];
    #pragma unroll
    for (int m=0;m<4;m++){
      av[m] = *(const short8*)(LX + (wr*64 + m*16 + lrow)*64 + kb);
      bv[m] = *(const short8*)(LY + (wc*64 + m*16 + lrow)*64 + kb);
    }
    #pragma unroll
    for (int m=0;m<4;m++)
      #pragma unroll
      for (int n=0;n<4;n++)
        acc[m][n] = __builtin_amdgcn_mfma_f32_16x16x32_bf16(av[m], bv[n], acc[m][n], 0, 0, 0);
    if (c<3) __syncthreads();
  }

  // diagonal: acc=0 -> key 0 = minimal (reference adds BIG)
  if (blockIdx.x == blockIdx.y && wr == wc && kgrp == (lrow >> 2)){
    #pragma unroll
    for (int r=0;r<4;r++)
      if ((lrow & 3) == r){
        #pragma unroll
        for (int m=0;m<4;m++) acc[m][m][r] = 0.0f;
      }
  }

  // packing + max-trees (v_fract / v_and_or / v_max3 shaped)
  const int colb_loc = wc*64 + lrow;
  u32 orvr[4];
  #pragma unroll
  for (int n=0;n<4;n++) orvr[n] = (u32)(127 - colb_loc - n*16);

  u32 pkc[4] = {0u,0u,0u,0u};
  u32 rpk[16];
  #pragma unroll
  for (int m=0;m<4;m++){
    #pragma unroll
    for (int r=0;r<4;r++){
      const u32 orvc = (u32)(63 - (m*16 + kgrp*4 + r));
      u32 kb2[4];
      #pragma unroll
      for (int n=0;n<4;n++)
        kb2[n] = __float_as_uint(fract1(acc[m][n][r]));
      const u32 b0 = (kb2[0] & 0xFFFFFF80u) | orvr[0];
      const u32 b1 = (kb2[1] & 0xFFFFFF80u) | orvr[1];
      const u32 b2 = (kb2[2] & 0xFFFFFF80u) | orvr[2];
      const u32 b3 = (kb2[3] & 0xFFFFFF80u) | orvr[3];
      rpk[m*4+r] = umax2(umax3(b0, b1, b2), b3);
      const u32 c0 = (kb2[0] & 0xFFFFFFC0u) | orvc;
      const u32 c1 = (kb2[1] & 0xFFFFFFC0u) | orvc;
      const u32 c2 = (kb2[2] & 0xFFFFFFC0u) | orvc;
      const u32 c3 = (kb2[3] & 0xFFFFFFC0u) | orvc;
      pkc[0] = umax2(pkc[0], c0);
      pkc[1] = umax2(pkc[1], c1);
      pkc[2] = umax2(pkc[2], c2);
      pkc[3] = umax2(pkc[3], c3);
    }
  }

  // col: combine across kgrp lanes (row id embedded -> shuffle-max keeps winner)
  #pragma unroll
  for (int n=0;n<4;n++){
    u32 o = (u32)__shfl_xor((int)pkc[n], 16, 64); pkc[n] = umax2(pkc[n], o);
    o = (u32)__shfl_xor((int)pkc[n], 32, 64);     pkc[n] = umax2(pkc[n], o);
  }

  __syncthreads();                                  // tiles consumed; reuse LDS
  u32* rowbuf = (u32*)S;                            // [128][36] u32 = 18KB
  u32* colred = (u32*)((char*)S + 20480);           // [2][128] u32 = 1KB
  {
    const int slot = wc*16 + lrow;
    #pragma unroll
    for (int m=0;m<4;m++)
      #pragma unroll
      for (int r=0;r<4;r++){
        const int row = wr*64 + m*16 + kgrp*4 + r;
        rowbuf[row*36 + slot] = rpk[m*4+r];
      }
    if (kgrp == 0){
      #pragma unroll
      for (int n=0;n<4;n++)
        colred[wr*128 + wc*64 + n*16 + lrow] = pkc[n];
    }
  }
  __syncthreads();

  if (tid < 128){
    const u32* base = rowbuf + tid*36;
    u32 best = 0u;
    #pragma unroll
    for (int q=0;q<8;q++){
      const uint4 t = *(const uint4*)(base + q*4);
      best = umax2(best, umax2(umax3(t.x, t.y, t.z), t.w));
    }
    const int colg = 127 - (int)(best & 127u);
    rowpart[((size_t)pair*64 + blockIdx.x)*CNT + (brow + tid)] =
        ((~best) & 0xFFFFE000u) | (u32)(bcol + colg);
  } else {
    const int c = tid - 128;
    const u32 a0 = colred[c], a1 = colred[128 + c];
    const u32 w = a1 > a0 ? a1 : a0;
    const int rloc = (a1 > a0 ? 64 : 0) + (63 - (int)(w & 63u));
    colpart[((size_t)pair*64 + blockIdx.y)*CNT + (bcol + c)] =
        ((~w) & 0xFFFFE000u) | (u32)(brow + rloc);
  }
#undef STAGEC
}

// fused: reduce 64 row/col partials + pick hard negative + exact f32 dots (renormalized
// from descs) + u,v + per-block moment partials
__global__ __launch_bounds__(256) void kpick(const float* __restrict__ descs,
    const u32* __restrict__ rowpart, const u32* __restrict__ colpart,
    float* __restrict__ pos, float* __restrict__ neg,
    float* __restrict__ u, float* __restrict__ v, float* __restrict__ mpart){
  __shared__ float sred[4][5];
  const int tid = threadIdx.x;
  const int w4 = tid >> 6, lane = tid & 63;
  const int e = blockIdx.x*4 + w4;                 // 0..24575
  const int p = e >> 13, i = e & (CNT-1);
  const int xo[3] = {0, 2*CNT, 4*CNT};
  const int yo[3] = {CNT, 5*CNT, 3*CNT};
  u32 rv = rowpart[((size_t)p*64 + lane)*CNT + i];
  u32 cv = colpart[((size_t)p*64 + lane)*CNT + i];
  #pragma unroll
  for (int m=1;m<64;m<<=1){
    u32 o = (u32)__shfl_xor((int)rv, m, 64); rv = o < rv ? o : rv;
    o = (u32)__shfl_xor((int)cv, m, 64);     cv = o < cv ? o : cv;
  }
  int orow;
  if ((rv & 0xFFFFE000u) < (cv & 0xFFFFE000u)) orow = yo[p] + (int)(rv & 0x1FFFu);
  else                                          orow = xo[p] + (int)(cv & 0x1FFFu);
  const float2 va = *(const float2*)(descs + (size_t)(xo[p]+i)*DIM + lane*2);
  const float2 vp = *(const float2*)(descs + (size_t)(yo[p]+i)*DIM + lane*2);
  const float2 vn = *(const float2*)(descs + (size_t)orow*DIM + lane*2);
  float saa = va.x*va.x + va.y*va.y;
  float spp = vp.x*vp.x + vp.y*vp.y;
  float snn = vn.x*vn.x + vn.y*vn.y;
  float sap = va.x*vp.x + va.y*vp.y;
  float san = va.x*vn.x + va.y*vn.y;
  #pragma unroll
  for (int m=1;m<64;m<<=1){
    saa += __shfl_xor(saa, m, 64);
    spp += __shfl_xor(spp, m, 64);
    snn += __shfl_xor(snn, m, 64);
    sap += __shfl_xor(sap, m, 64);
    san += __shfl_xor(san, m, 64);
  }
  if (lane == 0){
    const float dp = sap / (sqrtf(saa)*sqrtf(spp));
    const float dn = san / (sqrtf(saa)*sqrtf(snn));
    pos[p*CNT + i] = dp; neg[p*CNT + i] = dn;
    const float omp_ = 1.f - dp, sqp = sqrtf(2.f*omp_ + 1e-12f), up = omp_ - sqp;
    const float omn_ = 1.f - dn, sqn = sqrtf(2.f*omn_ + 1e-12f), un = omn_ - sqn;
    u[p*CNT + i] = up;           v[p*CNT + i] = sqp;
    u[3*CNT + p*CNT + i] = un;   v[3*CNT + p*CNT + i] = sqn;
    const float cup = up + 0.35f, cvp = sqp - 0.80f;
    const float cun = un + 0.35f, cvn = sqn - 0.80f;
    sred[w4][0] = up + un;
    sred[w4][1] = sqp + sqn;
    sred[w4][2] = cup*cup + cun*cun;
    sred[w4][3] = cup*cvp + cun*cvn;
    sred[w4][4] = cvp*cvp + cvn*cvn;
  }
  __syncthreads();
  if (tid < 5)
    mpart[blockIdx.x*5 + tid] = sred[0][tid] + sred[1][tid] + sred[2][tid] + sred[3][tid];
}

// combine moment partials; per-alpha mean & inv_std
__global__ __launch_bounds__(256) void kmom(const float* __restrict__ mpart,
    float* __restrict__ amean, float* __restrict__ aistd){
  __shared__ float red[4];
  __shared__ float sm[5];
  const int tid = threadIdx.x;
  float a0=0.f,a1=0.f,a2=0.f,a3=0.f,a4=0.f;
  for (int i = tid; i < 6144; i += 256){
    const float* mp = mpart + (size_t)i*5;
    a0+=mp[0]; a1+=mp[1]; a2+=mp[2]; a3+=mp[3]; a4+=mp[4];
  }
  a0 = block_sum(a0, red, tid);
  a1 = block_sum(a1, red, tid);
  a2 = block_sum(a2, red, tid);
  a3 = block_sum(a3, red, tid);
  a4 = block_sum(a4, red, tid);
  if (tid == 0){ sm[0]=a0; sm[1]=a1; sm[2]=a2; sm[3]=a3; sm[4]=a4; }
  __syncthreads();
  const float N = 49152.0f;
  const float mu_u = sm[0]/N, mu_v = sm[1]/N;
  const float du = mu_u + 0.35f, dv = mu_v - 0.80f;
  const float Suu = sm[2] - N*du*du;
  const float Suv = sm[3] - N*du*dv;
  const float Svv = sm[4] - N*dv*dv;
  if (tid < 200){
    const float a = -1.0f + 0.01f*(float)tid;
    amean[tid] = a*mu_u + mu_v;
    const float var = (a*a*Suu + 2.0f*a*Suv + Svv) / 49151.0f;
    aistd[tid] = 1.0f/sqrtf(var);
  }
}

// kbce: grid (200 alphas x 8 chunks); fast softplus partial sums
__global__ __launch_bounds__(256) void kbce(const float* __restrict__ u, const float* __restrict__ v,
    const float* __restrict__ amean, const float* __restrict__ aistd, float* __restrict__ psum){
  __shared__ float red[4];
  const int tid = threadIdx.x;
  const int a = blockIdx.x >> 3, c = blockIdx.x & 7;
  const float av = -1.0f + 0.01f*(float)a;
  const float mean = amean[a], istd = aistd[a];
  const int base = c*6144;
  float s = 0.0f;
  #pragma unroll 4
  for (int k = 0; k < 24; ++k){
    const int idx = base + k*256 + tid;
    const float z = (fmaf(av, u[idx], v[idx]) - mean) * istd;
    const float zz = (idx < 3*CNT) ? z : -z;
    s += fmaxf(zz, 0.0f) + __logf(1.0f + __expf(-fabsf(zz)));
  }
  s = block_sum(s, red, tid);
  if (tid == 0) psum[blockIdx.x] = s;
}

// argmin(bce) -> alpha; losses, mask ratio, l_mean; 8 outputs
__global__ __launch_bounds__(256) void kfinal(const float* __restrict__ pos, const float* __restrict__ neg,
    const float* __restrict__ psum, const float* __restrict__ l_a_adv, const float* __restrict__ l_p_adv,
    float* __restrict__ out){
  __shared__ float sbce[200];
  __shared__ float sal[2];
  __shared__ float red[4];
  const int tid = threadIdx.x;
  if (tid < 200){
    float s = 0.f;
    #pragma unroll
    for (int c=0;c<8;c++) s += psum[tid*8 + c];
    sbce[tid] = s;
  }
  __syncthreads();
  if (tid == 0){
    float best = sbce[0]; int bk = 0;
    for (int k=1;k<200;k++){
      const float vv = sbce[k];
      if (vv < best){ best = vv; bk = k; }
    }
    const float aopt = -1.0f + 0.01f*(float)bk;
    sal[0] = aopt;
    sal[1] = aopt * 0.005f;
  }
  __syncthreads();
  const float alpha = sal[1];

  float sc=0.f, sar=0.f, saa=0.f, sm=0.f, sla=0.f, slp=0.f;
  for (int i = tid; i < CNT; i += 256){
    const float pap = pos[i],        nap = neg[i];
    const float par = pos[CNT+i],    nar = neg[CNT+i];
    const float paa = pos[2*CNT+i],  naa = neg[2*CNT+i];
    const float cp = fminf(fmaxf(pap, -1.0f), 1.0f);
    const float cn = fminf(fmaxf(nap, -1.0f), 1.0f);
    const float m = (0.36f + acosf(cp) - acosf(cn) > 0.0f) ? 1.0f : 0.0f;
    #define DDIST(d) (alpha*(1.0f-(d)) + (1.0f-alpha)*sqrtf(2.0f*(1.0f-(d)) + 1e-12f))
    sc  += (DDIST(pap) - DDIST(nap)) * m;
    sar += (l_p_adv[i]*DDIST(par) - DDIST(nar)) * m;
    saa += (l_a_adv[i]*DDIST(paa) - DDIST(naa)) * m;
    sm  += m;
    sla += l_a_adv[i];
    slp += l_p_adv[i];
  }
  float vals[6] = {sc, sar, saa, sm, sla, slp};
  float tot[6];
  for (int vv=0; vv<6; vv++){
    tot[vv] = block_sum(vals[vv], red, tid);
  }
  if (tid == 0){
    const float lc  = tot[0] / (float)CNT;
    const float lar = tot[1] / (float)CNT;
    const float laa = tot[2] / (float)CNT;
    out[0] = (lc + lar + laa) / 3.0f;
    out[1] = lc;
    out[2] = lar;
    out[3] = laa;
    out[4] = (tot[4]/(float)CNT + tot[5]/(float)CNT) * 0.5f;
    out[5] = sal[1];
    out[6] = sal[0];
    out[7] = tot[3] / (float)CNT;
  }
}

extern "C" void kernel_launch(void* const* d_in, const int* in_sizes, int n_in,
                              void* d_out, int out_size, void* d_ws, size_t ws_size,
                              hipStream_t stream) {
  const float* descs = (const float*)d_in[0];
  const float* l_a   = (const float*)d_in[1];
  const float* l_p   = (const float*)d_in[2];
  float* out = (float*)d_out;
  char* ws = (char*)d_ws;

  float* pos = (float*)(ws + OFF_POS);
  float* neg = (float*)(ws + OFF_NEG);
  u32* rowpart = (u32*)(ws + OFF_ROWPART);
  u32* colpart = (u32*)(ws + OFF_COLPART);
  float* u     = (float*)(ws + OFF_U);
  float* v     = (float*)(ws + OFF_V);
  float* mpart = (float*)(ws + OFF_MPART);
  float* amean = (float*)(ws + OFF_AMEAN);
  float* aistd = (float*)(ws + OFF_AISTD);
  float* psum  = (float*)(ws + OFF_PSUM);
  unsigned int* xnb32 = (unsigned int*)(ws + OFF_XNB);
  const unsigned short* xnb = (const unsigned short*)(ws + OFF_XNB);

  knorm  <<<(6*CNT)/4, 256, 0, stream>>>(descs, xnb32);
  kgemm  <<<dim3(64,64,3), 256, 0, stream>>>(xnb, rowpart, colpart);
  kpick  <<<(3*CNT)/4, 256, 0, stream>>>(descs, rowpart, colpart, pos, neg, u, v, mpart);
  kmom   <<<1, 256, 0, stream>>>(mpart, amean, aistd);
  kbce   <<<1600, 256, 0, stream>>>(u, v, amean, aistd, psum);
  kfinal <<<1, 256, 0, stream>>>(pos, neg, psum, l_a, l_p, out);
}